// Round 15
// baseline (343.697 us; speedup 1.0000x reference)
//
#include <hip/hip_runtime.h>
#include <stdint.h>

typedef short bf16x8 __attribute__((ext_vector_type(8)));
typedef float f32x4 __attribute__((ext_vector_type(4)));
typedef float f32x16 __attribute__((ext_vector_type(16)));
typedef unsigned short u16;
typedef unsigned int u32;

__device__ __forceinline__ u16 f2bf(float f) {
    u32 x = __float_as_uint(f);
    x += 0x7fffu + ((x >> 16) & 1u);
    return (u16)(x >> 16);
}
__device__ __forceinline__ u32 pack_bf2(float a, float b) {
    return (u32)f2bf(a) | ((u32)f2bf(b) << 16);
}
__device__ __forceinline__ float bf2f(u16 v) {
    return __uint_as_float(((u32)v) << 16);
}

union Frag4 { u32 u[4]; bf16x8 v; };

// async global->LDS, 16B per lane; LDS dest is wave-uniform base + lane*16
__device__ __forceinline__ void gload16(const u16* g, u16* l) {
    __builtin_amdgcn_global_load_lds(
        (__attribute__((address_space(1))) void*)g,
        (__attribute__((address_space(3))) void*)l,
        16, 0, 0);
}

// ---------------- f32 -> bf16 cast, 8 elems/thread (G13: vectorized) --------
__global__ void cvt_f32_bf16(const float* __restrict__ in, u16* __restrict__ out, long n8) {
    long stride = (long)gridDim.x * blockDim.x;
    for (long i = (long)blockIdx.x * blockDim.x + threadIdx.x; i < n8; i += stride) {
        const float4* p = (const float4*)(in + i * 8);
        float4 a = p[0], b = p[1];
        uint4 o;
        o.x = pack_bf2(a.x, a.y);
        o.y = pack_bf2(a.z, a.w);
        o.z = pack_bf2(b.x, b.y);
        o.w = pack_bf2(b.z, b.w);
        ((uint4*)out)[i] = o;
    }
}

// ---------------- bf16 NT GEMM 256x256, BK=32: out = A*B^T + bias (bf16) ----
// 8 waves (2Mx4N, 128x64 out/wave). LDS 64KB (2 blocks/CU; 384-block grid
// fully co-resident, zero tail). Validated counted-vmcnt skeleton (rounds
// 7-13): stage(t+2) after read-barrier, vmcnt(4)=loads/tile mid-loop.
// LDS packing: 2 m-rows per 128B LDS row (lrow L holds m=2L @bytes 0-63,
// m=2L+1 @64-127), involution swizzle byte^=((L&7)<<4) on store-source and
// read (rule #21). Derived bank map: 8 lanes/bank-quad uniform = conflict-free.
__global__ __launch_bounds__(512, 2) void gemm256_nt(
    const u16* __restrict__ A, const u16* __restrict__ B,
    const float* __restrict__ bias, u16* __restrict__ out,
    int K, int ldo, int gxsh)
{
    __shared__ __align__(16) u16 lA[2 * 256 * 32];   // 32KB: 2 buf x 16KB
    __shared__ __align__(16) u16 lB[2 * 256 * 32];
    const int tid  = threadIdx.x;
    const int lane = tid & 63;
    const int w    = tid >> 6;           // 0..7
    const int wm = (w >> 2) * 128;       // 2 waves in M
    const int wn = (w & 3) * 64;         // 4 waves in N

    const int nwg = gridDim.x;           // % 8 == 0
    const int bid = blockIdx.x;
    const int swz = (bid & 7) * (nwg >> 3) + (bid >> 3);
    const int bm = (swz & ((1 << gxsh) - 1)) * 256;
    const int bn = (swz >> gxsh) * 256;

    const int NT = K >> 5;

    // staging: 16 chunks of 1KB per matrix per K-tile; chunk c = lrows 8c..8c+7
    // lane l -> stored byte l*16; logical byte = stored ^ ((l>>3)<<4)
    const int Ls   = (lane >> 3);                       // lrow within chunk
    const u32 lb   = (u32)(((lane & 7) * 16) ^ (Ls << 4)); // logical byte 0..112
    const int mpar = (int)(lb >> 6);                    // m parity bit
    const int ke   = (int)((lb & 63) >> 1);             // k elem 0/8/16/24

    auto stage = [&](int bb, int k0) {
#pragma unroll
        for (int i = 0; i < 2; ++i) {
            const int c = w * 2 + i;                    // chunk 0..15
            const int m = 2 * (c * 8 + Ls) + mpar;      // 0..255
            gload16(A + (size_t)(bm + m) * K + k0 + ke, lA + bb * 8192 + c * 512);
            gload16(B + (size_t)(bn + m) * K + k0 + ke, lB + bb * 8192 + c * 512);
        }
    };

    f32x4 acc[8][4];
#pragma unroll
    for (int i = 0; i < 8; ++i)
#pragma unroll
        for (int j = 0; j < 4; ++j)
#pragma unroll
            for (int r = 0; r < 4; ++r) acc[i][j][r] = 0.f;

    stage(0, 0);
    stage(1, 32);
    asm volatile("s_waitcnt vmcnt(4)" ::: "memory");
    __builtin_amdgcn_sched_barrier(0);
    __builtin_amdgcn_s_barrier();
    __builtin_amdgcn_sched_barrier(0);

    for (int t = 0; t < NT; ++t) {
        const int cur = t & 1;
        const char* pA = (const char*)(lA + cur * 8192);
        const char* pB = (const char*)(lB + cur * 8192);
        bf16x8 af[8], bfr[4];
#pragma unroll
        for (int f = 0; f < 8; ++f) {
            const int m = wm + f * 16 + (lane & 15);
            const u32 L = (u32)(m >> 1);
            const u32 b0 = (u32)((m & 1) * 64 + (lane >> 4) * 16);
            af[f] = *(const bf16x8*)(pA + L * 128 + (b0 ^ ((L & 7) << 4)));
        }
#pragma unroll
        for (int j = 0; j < 4; ++j) {
            const int n = wn + j * 16 + (lane & 15);
            const u32 L = (u32)(n >> 1);
            const u32 b0 = (u32)((n & 1) * 64 + (lane >> 4) * 16);
            bfr[j] = *(const bf16x8*)(pB + L * 128 + (b0 ^ ((L & 7) << 4)));
        }
        __builtin_amdgcn_s_setprio(1);
#pragma unroll
        for (int i = 0; i < 8; ++i)
#pragma unroll
            for (int j = 0; j < 4; ++j)
                acc[i][j] = __builtin_amdgcn_mfma_f32_16x16x32_bf16(af[i], bfr[j], acc[i][j], 0, 0, 0);
        __builtin_amdgcn_s_setprio(0);
        // all waves done reading buf cur
        __builtin_amdgcn_sched_barrier(0);
        __builtin_amdgcn_s_barrier();
        __builtin_amdgcn_sched_barrier(0);
        if (t + 2 < NT) {
            stage(cur, (t + 2) * 32);
            asm volatile("s_waitcnt vmcnt(4)" ::: "memory");
        } else {
            asm volatile("s_waitcnt vmcnt(0)" ::: "memory");
        }
        __builtin_amdgcn_sched_barrier(0);
        __builtin_amdgcn_s_barrier();
        __builtin_amdgcn_sched_barrier(0);
    }

    // epilogue: C/D layout col=lane&15, row=(lane>>4)*4+reg (m89-verified)
#pragma unroll
    for (int i = 0; i < 8; ++i) {
        int m0 = bm + wm + i * 16 + ((lane >> 4) << 2);
#pragma unroll
        for (int j = 0; j < 4; ++j) {
            int n = bn + wn + j * 16 + (lane & 15);
            float bv = bias[n];
#pragma unroll
            for (int r = 0; r < 4; ++r)
                out[(size_t)(m0 + r) * ldo + n] = f2bf(acc[i][j][r] + bv);
        }
    }
}

// ---------------- bf16 NT GEMM 128x128 (validated rounds 7-13) --------------
template<int OBF>
__global__ __launch_bounds__(256, 2) void gemm_nt(
    const u16* __restrict__ A, const u16* __restrict__ B,
    const float* __restrict__ bias, void* __restrict__ out,
    int K, int ldo, int gxsh)
{
    __shared__ __align__(16) u16 lA[2 * 128 * 64];
    __shared__ __align__(16) u16 lB[2 * 128 * 64];
    const int tid  = threadIdx.x;
    const int lane = tid & 63;
    const int w    = tid >> 6;
    const int wm = (w >> 1) * 64, wn = (w & 1) * 64;

    const int nwg = gridDim.x;
    const int bid = blockIdx.x;
    const int swz = (bid & 7) * (nwg >> 3) + (bid >> 3);
    const int bm = (swz & ((1 << gxsh) - 1)) * 128;
    const int bn = (swz >> gxsh) * 128;

    const int lr = lane >> 3;
    const u32 sb = (u32)((lane & 7) * 16);
    const int NT = K >> 6;

    auto stage = [&](int bb, int k0) {
#pragma unroll
        for (int i = 0; i < 4; ++i) {
            const int c = w * 4 + i;
            const int row = c * 8 + lr;
            const u32 col = (sb ^ ((u32)(row & 7) << 4)) >> 1;
            gload16(A + (size_t)(bm + row) * K + k0 + col, lA + bb * 8192 + c * 512);
            gload16(B + (size_t)(bn + row) * K + k0 + col, lB + bb * 8192 + c * 512);
        }
    };

    f32x4 acc[4][4];
#pragma unroll
    for (int i = 0; i < 4; ++i)
#pragma unroll
        for (int j = 0; j < 4; ++j)
#pragma unroll
            for (int r = 0; r < 4; ++r) acc[i][j][r] = 0.f;

    stage(0, 0);
    stage(1, 64);
    asm volatile("s_waitcnt vmcnt(8)" ::: "memory");
    __builtin_amdgcn_sched_barrier(0);
    __builtin_amdgcn_s_barrier();
    __builtin_amdgcn_sched_barrier(0);

    for (int t = 0; t < NT; ++t) {
        const int cur = t & 1;
        const char* pA = (const char*)(lA + cur * 8192);
        const char* pB = (const char*)(lB + cur * 8192);
#pragma unroll
        for (int kk = 0; kk < 2; ++kk) {
            bf16x8 af[4], bfr[4];
#pragma unroll
            for (int f = 0; f < 4; ++f) {
                const int m = wm + f * 16 + (lane & 15);
                const u32 byt = (u32)(kk * 64 + (lane >> 4) * 16) ^ ((u32)(m & 7) << 4);
                af[f]  = *(const bf16x8*)(pA + m * 128 + byt);
                const int n = wn + f * 16 + (lane & 15);
                const u32 bytb = (u32)(kk * 64 + (lane >> 4) * 16) ^ ((u32)(n & 7) << 4);
                bfr[f] = *(const bf16x8*)(pB + n * 128 + bytb);
            }
            __builtin_amdgcn_s_setprio(1);
#pragma unroll
            for (int i = 0; i < 4; ++i)
#pragma unroll
                for (int j = 0; j < 4; ++j)
                    acc[i][j] = __builtin_amdgcn_mfma_f32_16x16x32_bf16(af[i], bfr[j], acc[i][j], 0, 0, 0);
            __builtin_amdgcn_s_setprio(0);
        }
        __builtin_amdgcn_sched_barrier(0);
        __builtin_amdgcn_s_barrier();
        __builtin_amdgcn_sched_barrier(0);
        if (t + 2 < NT) {
            stage(cur, (t + 2) * 64);
            asm volatile("s_waitcnt vmcnt(8)" ::: "memory");
        } else {
            asm volatile("s_waitcnt vmcnt(0)" ::: "memory");
        }
        __builtin_amdgcn_sched_barrier(0);
        __builtin_amdgcn_s_barrier();
        __builtin_amdgcn_sched_barrier(0);
    }

#pragma unroll
    for (int i = 0; i < 4; ++i) {
        int m0 = bm + wm + i * 16 + ((lane >> 4) << 2);
#pragma unroll
        for (int j = 0; j < 4; ++j) {
            int n = bn + wn + j * 16 + (lane & 15);
            float bv = bias[n];
#pragma unroll
            for (int r = 0; r < 4; ++r) {
                float v = acc[i][j][r] + bv;
                if constexpr (OBF != 0)
                    ((u16*)out)[(size_t)(m0 + r) * ldo + n] = f2bf(v);
                else
                    ((float*)out)[(size_t)(m0 + r) * ldo + n] = v;
            }
        }
    }
}

// ---------------- V transpose: vt[b,h,d,t] <- qkv[b*2048+t][4096+h*128+d] ---
__global__ __launch_bounds__(256) void transpose_v(
    const u16* __restrict__ qkv, u16* __restrict__ vt)
{
    __shared__ u16 lt[64 * 64];
    const int tid = threadIdx.x;
    const int bid = blockIdx.x;
    const int tt    = bid & 31;
    const int dtile = (bid >> 5) & 1;
    const int h     = (bid >> 6) & 15;
    const int b     = bid >> 10;
    const u16* src = qkv + ((size_t)b * 2048 + tt * 64) * 6144 + 4096 + h * 128 + dtile * 64;

    const int r = tid >> 2, ce = (tid & 3) * 16;
    uint4 a0 = *(const uint4*)(src + (size_t)r * 6144 + ce);
    uint4 a1 = *(const uint4*)(src + (size_t)r * 6144 + ce + 8);
    const u32 swz = (u32)((r & 7) << 4);
    *(uint4*)((char*)lt + r * 128 + (((u32)(ce * 2)) ^ swz)) = a0;
    *(uint4*)((char*)lt + r * 128 + (((u32)(ce * 2 + 16)) ^ swz)) = a1;
    __syncthreads();

    const int d = tid >> 2;
    u16* dst = vt + ((size_t)(b * 16 + h) * 128 + dtile * 64 + d) * 2048 + tt * 64;
#pragma unroll
    for (int it = 0; it < 2; ++it) {
        const int t0 = (tid & 3) * 8 + it * 32;
        union { u16 hh[8]; uint4 q4; } u;
#pragma unroll
        for (int uu = 0; uu < 8; ++uu) {
            int trow = t0 + uu;
            u32 byt = (u32)(trow * 128) + (((u32)(d * 2)) ^ ((u32)((trow & 7) << 4)));
            u.hh[uu] = *(const u16*)((const char*)lt + byt);
        }
        *(uint4*)(dst + t0) = u.q4;
    }
}

// ---------------- causal flash attention (round-13 validated) ---------------
__constant__ unsigned char QT_TAB[30] = {11,11, 5,15,15,15,10,10,14,14,14, 9, 9, 4,13,13,13,12,12,12, 8, 8, 7, 7, 3, 6, 6, 2, 1, 0};
__constant__ unsigned char TLO_TAB[30]= { 0,24, 0, 0,22,43, 0,22, 0,20,40, 0,20, 0, 0,19,38, 0,18,36, 0,18, 0,16, 0, 0,14, 0, 0, 0};
__constant__ unsigned char THI_TAB[30]= {24,48,24,22,43,64,22,44,20,40,60,20,40,20,19,38,56,18,36,52,18,36,16,32,16,14,28,12, 8, 4};
__constant__ unsigned char SL_TAB[30] = {10,11,255,21,22,23, 8, 9,18,19,20, 6, 7,255,15,16,17,12,13,14, 4, 5, 2, 3,255, 0, 1,255,255,255};

__global__ __launch_bounds__(256) void attn_fwd(
    const u16* __restrict__ qkv, const u16* __restrict__ vt,
    u16* __restrict__ obuf, u16* __restrict__ pout, float* __restrict__ pml)
{
    __shared__ __align__(16) u16 lS[17408];
    const int tid  = threadIdx.x;
    const int lane = tid & 63;
    const int w    = tid >> 6;
    const int g    = lane >> 5;
    const int ql   = lane & 31;

    const int bid  = blockIdx.x;
    const int item = bid >> 5;
    const int bh   = bid & 31;
    const int qt   = QT_TAB[item];
    const int slot = SL_TAB[item];
    const int t_lo = TLO_TAB[item];
    const int t_hi = THI_TAB[item];
    const int b = bh >> 4, h = bh & 15;
    const size_t rowbase = (size_t)b * 2048;
    const int qb = qt * 128;
    const int qw = qb + w * 32;
    const int q  = qw + ql;

    const u16* Khead = qkv + rowbase * 6144 + 2048 + h * 128;  // ld 6144
    const u16* Vth   = vt + (size_t)bh * 128 * 2048;           // Vt[d][t]

    bf16x8 qf[8];
    {
        const u16* qrow = qkv + (rowbase + q) * 6144 + h * 128;
#pragma unroll
        for (int ch = 0; ch < 8; ++ch)
            qf[ch] = *(const bf16x8*)(qrow + ch * 16 + g * 8);
    }

    f32x16 acc[4];
#pragma unroll
    for (int dt = 0; dt < 4; ++dt)
#pragma unroll
        for (int r = 0; r < 16; ++r) acc[dt][r] = 0.f;

    float m_run = -1e30f, l_run = 0.f;
    const float C2 = 0.08838834764831845f * 1.44269504088896341f; // scale*log2e

    auto stage = [&](int bb, int t) {
        const int kb = t * 32;
#pragma unroll
        for (int i = 0; i < 2; ++i) {
            const int c = w * 2 + i;
            const int kr = c * 4 + (lane >> 4);
            const u32 kcol = (((u32)((lane & 15) * 16)) ^ ((u32)(kr & 7) << 4)) >> 1;
            gload16(Khead + (size_t)(kb + kr) * 6144 + kcol,
                    lS + bb * 4096 + c * 512);
            const int vr = c * 16 + (lane >> 2);
            const u32 vcol = (((u32)((lane & 3) * 16)) ^ ((u32)(vr & 3) << 4)) >> 1;
            gload16(Vth + (size_t)vr * 2048 + kb + vcol,
                    lS + 8192 + bb * 4096 + c * 512);
        }
    };

    stage(0, t_lo);
    __syncthreads();
    int buf = 0;

    for (int t = t_lo; t < t_hi; ++t) {
        const int kb = t * 32;
        if (t + 1 < t_hi) stage(buf ^ 1, t + 1);

        if (kb <= qw + 31) {
            const char* lKb = (const char*)(lS + buf * 4096);
            const char* lVb = (const char*)(lS + 8192 + buf * 4096);
            const bool diag = (kb == qw);

            bf16x8 kf[8];
            const u32 ksw = ((u32)ql & 7) << 4;
#pragma unroll
            for (int ch = 0; ch < 8; ++ch)
                kf[ch] = *(const bf16x8*)(lKb + ql * 256 + (((u32)(ch * 32 + g * 16)) ^ ksw));

            f32x16 s_;
#pragma unroll
            for (int r = 0; r < 16; ++r) s_[r] = 0.f;
            __builtin_amdgcn_s_setprio(1);
#pragma unroll
            for (int ch = 0; ch < 8; ++ch)
                s_ = __builtin_amdgcn_mfma_f32_32x32x16_bf16(kf[ch], qf[ch], s_, 0, 0, 0);
            __builtin_amdgcn_s_setprio(0);

            float p[16];
            float tmax = -1e30f;
#pragma unroll
            for (int r = 0; r < 16; ++r) {
                int crow = (r & 3) + 8 * (r >> 2) + 4 * g;
                float v = s_[r];
                if (diag && (crow > ql)) v = -1e30f;   // causal mask
                p[r] = v;
                tmax = fmaxf(tmax, v);
            }
            tmax = fmaxf(tmax, __shfl_xor(tmax, 32));
            if (!__all(tmax <= m_run + 8.0f)) {
                float mnew  = fmaxf(m_run, tmax);
                float alpha = exp2f((m_run - mnew) * C2);
#pragma unroll
                for (int dt = 0; dt < 4; ++dt) acc[dt] = acc[dt] * alpha;
                l_run *= alpha;
                m_run = mnew;
            }
            float ssum = 0.f;
#pragma unroll
            for (int r = 0; r < 16; ++r) {
                float e = exp2f((p[r] - m_run) * C2);
                p[r] = e;
                ssum += e;
            }
            ssum += __shfl_xor(ssum, 32);
            l_run += ssum;

            u32 wb[8], sw[8];
#pragma unroll
            for (int j = 0; j < 8; ++j) wb[j] = pack_bf2(p[2 * j], p[2 * j + 1]);
#pragma unroll
            for (int j = 0; j < 8; ++j) sw[j] = __shfl_xor(wb[j], 32);
            Frag4 pf0, pf1;
#pragma unroll
            for (int u = 0; u < 4; ++u) {
                const bool own = (g == (u >> 1));
                pf0.u[u] = own ? wb[2 * g + (u & 1)]     : sw[2 * g + (u & 1)];
                pf1.u[u] = own ? wb[4 + 2 * g + (u & 1)] : sw[4 + 2 * g + (u & 1)];
            }

            __builtin_amdgcn_s_setprio(1);
#pragma unroll
            for (int dt = 0; dt < 4; ++dt) {
                const u32 vrow = (u32)(dt * 32 + ql);
                const u32 vsw = (vrow & 3) << 4;
                bf16x8 v0 = *(const bf16x8*)(lVb + vrow * 64 + (((u32)(g * 16)) ^ vsw));
                bf16x8 v1 = *(const bf16x8*)(lVb + vrow * 64 + (((u32)(32 + g * 16)) ^ vsw));
                acc[dt] = __builtin_amdgcn_mfma_f32_32x32x16_bf16(v0, pf0.v, acc[dt], 0, 0, 0);
                acc[dt] = __builtin_amdgcn_mfma_f32_32x32x16_bf16(v1, pf1.v, acc[dt], 0, 0, 0);
            }
            __builtin_amdgcn_s_setprio(0);
        }
        __syncthreads();
        buf ^= 1;
    }

    // epilogue via LDS for coalesced global stores (validated round 13)
    const float scale = (slot == 255) ? (1.0f / l_run) : 1.0f;
    u16* lO = lS + w * 4352;
#pragma unroll
    for (int dt = 0; dt < 4; ++dt) {
#pragma unroll
        for (int rr = 0; rr < 4; ++rr) {
            int d0 = dt * 32 + rr * 8 + g * 4;
            int r0 = rr * 4;
            u32* dst = (u32*)(lO + ql * 136 + d0);
            dst[0] = pack_bf2(acc[dt][r0] * scale,     acc[dt][r0 + 1] * scale);
            dst[1] = pack_bf2(acc[dt][r0 + 2] * scale, acc[dt][r0 + 3] * scale);
        }
    }
    if (slot != 255 && g == 0) {
        const int sg = bh * 24 + slot;
        float2* pm = (float2*)pml + sg * 128 + (w * 32 + ql);
        *pm = make_float2(m_run, l_run);
    }
    __syncthreads();

    u16* gbase;
    size_t rstride;
    if (slot == 255) {
        gbase = obuf + (rowbase + qw) * 2048 + h * 128;
        rstride = 2048;
    } else {
        const int sg = bh * 24 + slot;
        gbase = pout + (size_t)sg * 16384 + (size_t)(w * 32) * 128;
        rstride = 128;
    }
    const int eo = (lane & 15) * 8;
#pragma unroll
    for (int pass = 0; pass < 8; ++pass) {
        const int row = pass * 4 + (lane >> 4);
        bf16x8 v = *(const bf16x8*)(lO + row * 136 + eo);
        *(bf16x8*)(gbase + (size_t)row * rstride + eo) = v;
    }
}

// ---------------- merge the KV-chunk partials (qt >= 6, fan-in 2 or 3) ------
__global__ __launch_bounds__(256) void attn_merge(
    const u16* __restrict__ pout, const float* __restrict__ pml,
    u16* __restrict__ obuf)
{
    const int bid = blockIdx.x;          // 320 = j(10) x bh(32)
    const int bh = bid & 31, j = bid >> 5;
    const int qt = 6 + j;
    const int b = bh >> 4, h = bh & 15;
    const int tid = threadIdx.x;
    const int f  = (qt < 12) ? 2 : 3;
    const int sb = (qt < 12) ? (qt - 6) * 2 : 12 + (qt - 12) * 3;
    const int base = bh * 24 + sb;
    const float C2 = 0.08838834764831845f * 1.44269504088896341f;
    const int eo = (tid & 15) * 8;

#pragma unroll
    for (int pass = 0; pass < 8; ++pass) {
        const int row = pass * 16 + (tid >> 4);   // qloc 0..127
        float mv[3], lv[3], wv[3];
        float ms = -1e30f;
#pragma unroll
        for (int i = 0; i < 3; ++i) {
            if (i < f) {
                float2 ml = ((const float2*)pml)[(base + i) * 128 + row];
                mv[i] = ml.x; lv[i] = ml.y;
                ms = fmaxf(ms, ml.x);
            }
        }
        float L = 0.f;
#pragma unroll
        for (int i = 0; i < 3; ++i) {
            if (i < f) {
                wv[i] = exp2f((mv[i] - ms) * C2);
                L += lv[i] * wv[i];
            }
        }
        const float inv = 1.0f / L;

        float o[8];
#pragma unroll
        for (int e = 0; e < 8; ++e) o[e] = 0.f;
#pragma unroll
        for (int i = 0; i < 3; ++i) {
            if (i < f) {
                bf16x8 v = *(const bf16x8*)(pout + (size_t)(base + i) * 16384
                                            + (size_t)row * 128 + eo);
#pragma unroll
                for (int e = 0; e < 8; ++e) o[e] += wv[i] * bf2f((u16)v[e]);
            }
        }
        u16* orow = obuf + ((size_t)b * 2048 + qt * 128 + row) * 2048 + h * 128 + eo;
#pragma unroll
        for (int e = 0; e < 8; e += 2)
            *(u32*)(orow + e) = pack_bf2(o[e] * inv, o[e + 1] * inv);
    }
}

extern "C" void kernel_launch(void* const* d_in, const int* in_sizes, int n_in,
                              void* d_out, int out_size, void* d_ws, size_t ws_size,
                              hipStream_t stream) {
    (void)in_sizes; (void)n_in; (void)out_size; (void)ws_size;
    const float* x    = (const float*)d_in[0];
    const float* Wqkv = (const float*)d_in[1];
    const float* bqkv = (const float*)d_in[2];
    const float* Wout = (const float*)d_in[3];
    const float* bout = (const float*)d_in[4];

    char* ws = (char*)d_ws;
    u16* xb  = (u16*)ws;                        // [4096,2048] bf16, 16 MB
    u16* wqb = (u16*)(ws + (size_t)16777216);   // [6144,2048] bf16, 24 MB
    u16* qkv = (u16*)(ws + (size_t)41943040);   // [4096,6144] bf16, 48 MB
    u16* ob  = xb;   // attention out reuses xb (x dead after GEMM1)
    u16* vtb = wqb;  // V^T [32,128,2048] bf16 16 MB reuses wqb
    u16* wob = wqb;  // W_out bf16 reuses wqb again (vtb dead after attn)
    float* pml = (float*)(ws + (size_t)33554432);  // 768KB in wqb tail hole
    u16* pO  = (u16*)d_out;  // 24 MB bf16 partials: d_out is free scratch
                             // until gemm2 overwrites it

    cvt_f32_bf16<<<2048, 256, 0, stream>>>(x, xb, 8388608L / 8);
    cvt_f32_bf16<<<2048, 256, 0, stream>>>(Wqkv, wqb, 12582912L / 8);
    // 256^2 tile BK=32: grid 16 x 24 = 384 (divisible by 8), fully resident
    gemm256_nt<<<384, 512, 0, stream>>>(xb, wqb, bqkv, qkv, 2048, 6144, 4);
    transpose_v<<<2048, 256, 0, stream>>>(qkv, vtb);
    attn_fwd<<<960, 256, 0, stream>>>(qkv, vtb, ob, pO, pml);
    attn_merge<<<320, 256, 0, stream>>>(pO, pml, ob);
    cvt_f32_bf16<<<2048, 256, 0, stream>>>(Wout, wob, 4194304L / 8);
    gemm_nt<0><<<512, 256, 0, stream>>>(ob, wob, bout, d_out, 2048, 2048, 5);
}

// Round 16
// 299.963 us; speedup vs baseline: 1.1458x; 1.1458x over previous
//
#include <hip/hip_runtime.h>
#include <stdint.h>

typedef short bf16x8 __attribute__((ext_vector_type(8)));
typedef float f32x4 __attribute__((ext_vector_type(4)));
typedef float f32x16 __attribute__((ext_vector_type(16)));
typedef unsigned short u16;
typedef unsigned int u32;

__device__ __forceinline__ u16 f2bf(float f) {
    u32 x = __float_as_uint(f);
    x += 0x7fffu + ((x >> 16) & 1u);
    return (u16)(x >> 16);
}
__device__ __forceinline__ u32 pack_bf2(float a, float b) {
    return (u32)f2bf(a) | ((u32)f2bf(b) << 16);
}
__device__ __forceinline__ float bf2f(u16 v) {
    return __uint_as_float(((u32)v) << 16);
}

union Frag4 { u32 u[4]; bf16x8 v; };

// async global->LDS, 16B per lane; LDS dest is wave-uniform base + lane*16
__device__ __forceinline__ void gload16(const u16* g, u16* l) {
    __builtin_amdgcn_global_load_lds(
        (__attribute__((address_space(1))) void*)g,
        (__attribute__((address_space(3))) void*)l,
        16, 0, 0);
}

// ---------------- f32 -> bf16 cast, 8 elems/thread (G13: vectorized) --------
__global__ void cvt_f32_bf16(const float* __restrict__ in, u16* __restrict__ out, long n8) {
    long stride = (long)gridDim.x * blockDim.x;
    for (long i = (long)blockIdx.x * blockDim.x + threadIdx.x; i < n8; i += stride) {
        const float4* p = (const float4*)(in + i * 8);
        float4 a = p[0], b = p[1];
        uint4 o;
        o.x = pack_bf2(a.x, a.y);
        o.y = pack_bf2(a.z, a.w);
        o.z = pack_bf2(b.x, b.y);
        o.w = pack_bf2(b.z, b.w);
        ((uint4*)out)[i] = o;
    }
}

// ---------------- bf16 NT GEMM 128x128, 8 waves (gemm1) ---------------------
// Same validated 2-barrier counted-vmcnt skeleton (rounds 7-13), same 64KB
// dbuf LDS (2 blocks/CU), but 512 threads: 8 waves of 64x32 output each ->
// 16 waves/CU (vs 8) for latency/drain hiding. Stage: 2 A + 2 B chunks/wave
// (4 gloads/thread/tile, vmcnt(4) invariant identical to the 4-wave kernel).
__global__ __launch_bounds__(512, 2) void gemm128_8w(
    const u16* __restrict__ A, const u16* __restrict__ B,
    const float* __restrict__ bias, u16* __restrict__ out,
    int K, int ldo, int gxsh)
{
    __shared__ __align__(16) u16 lA[2 * 128 * 64];
    __shared__ __align__(16) u16 lB[2 * 128 * 64];
    const int tid  = threadIdx.x;
    const int lane = tid & 63;
    const int w    = tid >> 6;            // 0..7
    const int wm = (w >> 2) * 64;         // 2 waves in M
    const int wn = (w & 3) * 32;          // 4 waves in N

    const int nwg = gridDim.x;
    const int bid = blockIdx.x;
    const int swz = (bid & 7) * (nwg >> 3) + (bid >> 3);
    const int bm = (swz & ((1 << gxsh) - 1)) * 128;
    const int bn = (swz >> gxsh) * 128;

    const int lr = lane >> 3;
    const u32 sb = (u32)((lane & 7) * 16);
    const int NT = K >> 6;

    auto stage = [&](int bb, int k0) {
#pragma unroll
        for (int i = 0; i < 2; ++i) {
            const int c = w * 2 + i;              // chunk 0..15
            const int row = c * 8 + lr;
            const u32 col = (sb ^ ((u32)(row & 7) << 4)) >> 1;
            gload16(A + (size_t)(bm + row) * K + k0 + col, lA + bb * 8192 + c * 512);
            gload16(B + (size_t)(bn + row) * K + k0 + col, lB + bb * 8192 + c * 512);
        }
    };

    f32x4 acc[4][2];
#pragma unroll
    for (int i = 0; i < 4; ++i)
#pragma unroll
        for (int j = 0; j < 2; ++j)
#pragma unroll
            for (int r = 0; r < 4; ++r) acc[i][j][r] = 0.f;

    stage(0, 0);
    stage(1, 64);
    asm volatile("s_waitcnt vmcnt(4)" ::: "memory");
    __builtin_amdgcn_sched_barrier(0);
    __builtin_amdgcn_s_barrier();
    __builtin_amdgcn_sched_barrier(0);

    for (int t = 0; t < NT; ++t) {
        const int cur = t & 1;
        const char* pA = (const char*)(lA + cur * 8192);
        const char* pB = (const char*)(lB + cur * 8192);
#pragma unroll
        for (int kk = 0; kk < 2; ++kk) {
            bf16x8 af[4], bfr[2];
#pragma unroll
            for (int f = 0; f < 4; ++f) {
                const int m = wm + f * 16 + (lane & 15);
                const u32 byt = (u32)(kk * 64 + (lane >> 4) * 16) ^ ((u32)(m & 7) << 4);
                af[f] = *(const bf16x8*)(pA + m * 128 + byt);
            }
#pragma unroll
            for (int j = 0; j < 2; ++j) {
                const int n = wn + j * 16 + (lane & 15);
                const u32 byt = (u32)(kk * 64 + (lane >> 4) * 16) ^ ((u32)(n & 7) << 4);
                bfr[j] = *(const bf16x8*)(pB + n * 128 + byt);
            }
            __builtin_amdgcn_s_setprio(1);
#pragma unroll
            for (int i = 0; i < 4; ++i)
#pragma unroll
                for (int j = 0; j < 2; ++j)
                    acc[i][j] = __builtin_amdgcn_mfma_f32_16x16x32_bf16(af[i], bfr[j], acc[i][j], 0, 0, 0);
            __builtin_amdgcn_s_setprio(0);
        }
        __builtin_amdgcn_sched_barrier(0);
        __builtin_amdgcn_s_barrier();
        __builtin_amdgcn_sched_barrier(0);
        if (t + 2 < NT) {
            stage(cur, (t + 2) * 64);
            asm volatile("s_waitcnt vmcnt(4)" ::: "memory");
        } else {
            asm volatile("s_waitcnt vmcnt(0)" ::: "memory");
        }
        __builtin_amdgcn_sched_barrier(0);
        __builtin_amdgcn_s_barrier();
        __builtin_amdgcn_sched_barrier(0);
    }

    // epilogue: C/D layout col=lane&15, row=(lane>>4)*4+reg (m89-verified)
#pragma unroll
    for (int i = 0; i < 4; ++i) {
        int m0 = bm + wm + i * 16 + ((lane >> 4) << 2);
#pragma unroll
        for (int j = 0; j < 2; ++j) {
            int n = bn + wn + j * 16 + (lane & 15);
            float bv = bias[n];
#pragma unroll
            for (int r = 0; r < 4; ++r)
                out[(size_t)(m0 + r) * ldo + n] = f2bf(acc[i][j][r] + bv);
        }
    }
}

// ---------------- bf16 NT GEMM 128x128, 4 waves (validated; gemm2) ----------
template<int OBF>
__global__ __launch_bounds__(256, 2) void gemm_nt(
    const u16* __restrict__ A, const u16* __restrict__ B,
    const float* __restrict__ bias, void* __restrict__ out,
    int K, int ldo, int gxsh)
{
    __shared__ __align__(16) u16 lA[2 * 128 * 64];
    __shared__ __align__(16) u16 lB[2 * 128 * 64];
    const int tid  = threadIdx.x;
    const int lane = tid & 63;
    const int w    = tid >> 6;
    const int wm = (w >> 1) * 64, wn = (w & 1) * 64;

    const int nwg = gridDim.x;
    const int bid = blockIdx.x;
    const int swz = (bid & 7) * (nwg >> 3) + (bid >> 3);
    const int bm = (swz & ((1 << gxsh) - 1)) * 128;
    const int bn = (swz >> gxsh) * 128;

    const int lr = lane >> 3;
    const u32 sb = (u32)((lane & 7) * 16);
    const int NT = K >> 6;

    auto stage = [&](int bb, int k0) {
#pragma unroll
        for (int i = 0; i < 4; ++i) {
            const int c = w * 4 + i;
            const int row = c * 8 + lr;
            const u32 col = (sb ^ ((u32)(row & 7) << 4)) >> 1;
            gload16(A + (size_t)(bm + row) * K + k0 + col, lA + bb * 8192 + c * 512);
            gload16(B + (size_t)(bn + row) * K + k0 + col, lB + bb * 8192 + c * 512);
        }
    };

    f32x4 acc[4][4];
#pragma unroll
    for (int i = 0; i < 4; ++i)
#pragma unroll
        for (int j = 0; j < 4; ++j)
#pragma unroll
            for (int r = 0; r < 4; ++r) acc[i][j][r] = 0.f;

    stage(0, 0);
    stage(1, 64);
    asm volatile("s_waitcnt vmcnt(8)" ::: "memory");
    __builtin_amdgcn_sched_barrier(0);
    __builtin_amdgcn_s_barrier();
    __builtin_amdgcn_sched_barrier(0);

    for (int t = 0; t < NT; ++t) {
        const int cur = t & 1;
        const char* pA = (const char*)(lA + cur * 8192);
        const char* pB = (const char*)(lB + cur * 8192);
#pragma unroll
        for (int kk = 0; kk < 2; ++kk) {
            bf16x8 af[4], bfr[4];
#pragma unroll
            for (int f = 0; f < 4; ++f) {
                const int m = wm + f * 16 + (lane & 15);
                const u32 byt = (u32)(kk * 64 + (lane >> 4) * 16) ^ ((u32)(m & 7) << 4);
                af[f]  = *(const bf16x8*)(pA + m * 128 + byt);
                const int n = wn + f * 16 + (lane & 15);
                const u32 bytb = (u32)(kk * 64 + (lane >> 4) * 16) ^ ((u32)(n & 7) << 4);
                bfr[f] = *(const bf16x8*)(pB + n * 128 + bytb);
            }
            __builtin_amdgcn_s_setprio(1);
#pragma unroll
            for (int i = 0; i < 4; ++i)
#pragma unroll
                for (int j = 0; j < 4; ++j)
                    acc[i][j] = __builtin_amdgcn_mfma_f32_16x16x32_bf16(af[i], bfr[j], acc[i][j], 0, 0, 0);
            __builtin_amdgcn_s_setprio(0);
        }
        __builtin_amdgcn_sched_barrier(0);
        __builtin_amdgcn_s_barrier();
        __builtin_amdgcn_sched_barrier(0);
        if (t + 2 < NT) {
            stage(cur, (t + 2) * 64);
            asm volatile("s_waitcnt vmcnt(8)" ::: "memory");
        } else {
            asm volatile("s_waitcnt vmcnt(0)" ::: "memory");
        }
        __builtin_amdgcn_sched_barrier(0);
        __builtin_amdgcn_s_barrier();
        __builtin_amdgcn_sched_barrier(0);
    }

#pragma unroll
    for (int i = 0; i < 4; ++i) {
        int m0 = bm + wm + i * 16 + ((lane >> 4) << 2);
#pragma unroll
        for (int j = 0; j < 4; ++j) {
            int n = bn + wn + j * 16 + (lane & 15);
            float bv = bias[n];
#pragma unroll
            for (int r = 0; r < 4; ++r) {
                float v = acc[i][j][r] + bv;
                if constexpr (OBF != 0)
                    ((u16*)out)[(size_t)(m0 + r) * ldo + n] = f2bf(v);
                else
                    ((float*)out)[(size_t)(m0 + r) * ldo + n] = v;
            }
        }
    }
}

// ---------------- V transpose: vt[b,h,d,t] <- qkv[b*2048+t][4096+h*128+d] ---
__global__ __launch_bounds__(256) void transpose_v(
    const u16* __restrict__ qkv, u16* __restrict__ vt)
{
    __shared__ u16 lt[64 * 64];
    const int tid = threadIdx.x;
    const int bid = blockIdx.x;
    const int tt    = bid & 31;
    const int dtile = (bid >> 5) & 1;
    const int h     = (bid >> 6) & 15;
    const int b     = bid >> 10;
    const u16* src = qkv + ((size_t)b * 2048 + tt * 64) * 6144 + 4096 + h * 128 + dtile * 64;

    const int r = tid >> 2, ce = (tid & 3) * 16;
    uint4 a0 = *(const uint4*)(src + (size_t)r * 6144 + ce);
    uint4 a1 = *(const uint4*)(src + (size_t)r * 6144 + ce + 8);
    const u32 swz = (u32)((r & 7) << 4);
    *(uint4*)((char*)lt + r * 128 + (((u32)(ce * 2)) ^ swz)) = a0;
    *(uint4*)((char*)lt + r * 128 + (((u32)(ce * 2 + 16)) ^ swz)) = a1;
    __syncthreads();

    const int d = tid >> 2;
    u16* dst = vt + ((size_t)(b * 16 + h) * 128 + dtile * 64 + d) * 2048 + tt * 64;
#pragma unroll
    for (int it = 0; it < 2; ++it) {
        const int t0 = (tid & 3) * 8 + it * 32;
        union { u16 hh[8]; uint4 q4; } u;
#pragma unroll
        for (int uu = 0; uu < 8; ++uu) {
            int trow = t0 + uu;
            u32 byt = (u32)(trow * 128) + (((u32)(d * 2)) ^ ((u32)((trow & 7) << 4)));
            u.hh[uu] = *(const u16*)((const char*)lt + byt);
        }
        *(uint4*)(dst + t0) = u.q4;
    }
}

// ---------------- causal flash attention (round-13 validated) ---------------
__constant__ unsigned char QT_TAB[30] = {11,11, 5,15,15,15,10,10,14,14,14, 9, 9, 4,13,13,13,12,12,12, 8, 8, 7, 7, 3, 6, 6, 2, 1, 0};
__constant__ unsigned char TLO_TAB[30]= { 0,24, 0, 0,22,43, 0,22, 0,20,40, 0,20, 0, 0,19,38, 0,18,36, 0,18, 0,16, 0, 0,14, 0, 0, 0};
__constant__ unsigned char THI_TAB[30]= {24,48,24,22,43,64,22,44,20,40,60,20,40,20,19,38,56,18,36,52,18,36,16,32,16,14,28,12, 8, 4};
__constant__ unsigned char SL_TAB[30] = {10,11,255,21,22,23, 8, 9,18,19,20, 6, 7,255,15,16,17,12,13,14, 4, 5, 2, 3,255, 0, 1,255,255,255};

__global__ __launch_bounds__(256) void attn_fwd(
    const u16* __restrict__ qkv, const u16* __restrict__ vt,
    u16* __restrict__ obuf, u16* __restrict__ pout, float* __restrict__ pml)
{
    __shared__ __align__(16) u16 lS[17408];
    const int tid  = threadIdx.x;
    const int lane = tid & 63;
    const int w    = tid >> 6;
    const int g    = lane >> 5;
    const int ql   = lane & 31;

    const int bid  = blockIdx.x;
    const int item = bid >> 5;
    const int bh   = bid & 31;
    const int qt   = QT_TAB[item];
    const int slot = SL_TAB[item];
    const int t_lo = TLO_TAB[item];
    const int t_hi = THI_TAB[item];
    const int b = bh >> 4, h = bh & 15;
    const size_t rowbase = (size_t)b * 2048;
    const int qb = qt * 128;
    const int qw = qb + w * 32;
    const int q  = qw + ql;

    const u16* Khead = qkv + rowbase * 6144 + 2048 + h * 128;  // ld 6144
    const u16* Vth   = vt + (size_t)bh * 128 * 2048;           // Vt[d][t]

    bf16x8 qf[8];
    {
        const u16* qrow = qkv + (rowbase + q) * 6144 + h * 128;
#pragma unroll
        for (int ch = 0; ch < 8; ++ch)
            qf[ch] = *(const bf16x8*)(qrow + ch * 16 + g * 8);
    }

    f32x16 acc[4];
#pragma unroll
    for (int dt = 0; dt < 4; ++dt)
#pragma unroll
        for (int r = 0; r < 16; ++r) acc[dt][r] = 0.f;

    float m_run = -1e30f, l_run = 0.f;
    const float C2 = 0.08838834764831845f * 1.44269504088896341f; // scale*log2e

    auto stage = [&](int bb, int t) {
        const int kb = t * 32;
#pragma unroll
        for (int i = 0; i < 2; ++i) {
            const int c = w * 2 + i;
            const int kr = c * 4 + (lane >> 4);
            const u32 kcol = (((u32)((lane & 15) * 16)) ^ ((u32)(kr & 7) << 4)) >> 1;
            gload16(Khead + (size_t)(kb + kr) * 6144 + kcol,
                    lS + bb * 4096 + c * 512);
            const int vr = c * 16 + (lane >> 2);
            const u32 vcol = (((u32)((lane & 3) * 16)) ^ ((u32)(vr & 3) << 4)) >> 1;
            gload16(Vth + (size_t)vr * 2048 + kb + vcol,
                    lS + 8192 + bb * 4096 + c * 512);
        }
    };

    stage(0, t_lo);
    __syncthreads();
    int buf = 0;

    for (int t = t_lo; t < t_hi; ++t) {
        const int kb = t * 32;
        if (t + 1 < t_hi) stage(buf ^ 1, t + 1);

        if (kb <= qw + 31) {
            const char* lKb = (const char*)(lS + buf * 4096);
            const char* lVb = (const char*)(lS + 8192 + buf * 4096);
            const bool diag = (kb == qw);

            bf16x8 kf[8];
            const u32 ksw = ((u32)ql & 7) << 4;
#pragma unroll
            for (int ch = 0; ch < 8; ++ch)
                kf[ch] = *(const bf16x8*)(lKb + ql * 256 + (((u32)(ch * 32 + g * 16)) ^ ksw));

            f32x16 s_;
#pragma unroll
            for (int r = 0; r < 16; ++r) s_[r] = 0.f;
            __builtin_amdgcn_s_setprio(1);
#pragma unroll
            for (int ch = 0; ch < 8; ++ch)
                s_ = __builtin_amdgcn_mfma_f32_32x32x16_bf16(kf[ch], qf[ch], s_, 0, 0, 0);
            __builtin_amdgcn_s_setprio(0);

            float p[16];
            float tmax = -1e30f;
#pragma unroll
            for (int r = 0; r < 16; ++r) {
                int crow = (r & 3) + 8 * (r >> 2) + 4 * g;
                float v = s_[r];
                if (diag && (crow > ql)) v = -1e30f;   // causal mask
                p[r] = v;
                tmax = fmaxf(tmax, v);
            }
            tmax = fmaxf(tmax, __shfl_xor(tmax, 32));
            if (!__all(tmax <= m_run + 8.0f)) {
                float mnew  = fmaxf(m_run, tmax);
                float alpha = exp2f((m_run - mnew) * C2);
#pragma unroll
                for (int dt = 0; dt < 4; ++dt) acc[dt] = acc[dt] * alpha;
                l_run *= alpha;
                m_run = mnew;
            }
            float ssum = 0.f;
#pragma unroll
            for (int r = 0; r < 16; ++r) {
                float e = exp2f((p[r] - m_run) * C2);
                p[r] = e;
                ssum += e;
            }
            ssum += __shfl_xor(ssum, 32);
            l_run += ssum;

            u32 wb[8], sw[8];
#pragma unroll
            for (int j = 0; j < 8; ++j) wb[j] = pack_bf2(p[2 * j], p[2 * j + 1]);
#pragma unroll
            for (int j = 0; j < 8; ++j) sw[j] = __shfl_xor(wb[j], 32);
            Frag4 pf0, pf1;
#pragma unroll
            for (int u = 0; u < 4; ++u) {
                const bool own = (g == (u >> 1));
                pf0.u[u] = own ? wb[2 * g + (u & 1)]     : sw[2 * g + (u & 1)];
                pf1.u[u] = own ? wb[4 + 2 * g + (u & 1)] : sw[4 + 2 * g + (u & 1)];
            }

            __builtin_amdgcn_s_setprio(1);
#pragma unroll
            for (int dt = 0; dt < 4; ++dt) {
                const u32 vrow = (u32)(dt * 32 + ql);
                const u32 vsw = (vrow & 3) << 4;
                bf16x8 v0 = *(const bf16x8*)(lVb + vrow * 64 + (((u32)(g * 16)) ^ vsw));
                bf16x8 v1 = *(const bf16x8*)(lVb + vrow * 64 + (((u32)(32 + g * 16)) ^ vsw));
                acc[dt] = __builtin_amdgcn_mfma_f32_32x32x16_bf16(v0, pf0.v, acc[dt], 0, 0, 0);
                acc[dt] = __builtin_amdgcn_mfma_f32_32x32x16_bf16(v1, pf1.v, acc[dt], 0, 0, 0);
            }
            __builtin_amdgcn_s_setprio(0);
        }
        __syncthreads();
        buf ^= 1;
    }

    // epilogue via LDS for coalesced global stores (validated round 13)
    const float scale = (slot == 255) ? (1.0f / l_run) : 1.0f;
    u16* lO = lS + w * 4352;
#pragma unroll
    for (int dt = 0; dt < 4; ++dt) {
#pragma unroll
        for (int rr = 0; rr < 4; ++rr) {
            int d0 = dt * 32 + rr * 8 + g * 4;
            int r0 = rr * 4;
            u32* dst = (u32*)(lO + ql * 136 + d0);
            dst[0] = pack_bf2(acc[dt][r0] * scale,     acc[dt][r0 + 1] * scale);
            dst[1] = pack_bf2(acc[dt][r0 + 2] * scale, acc[dt][r0 + 3] * scale);
        }
    }
    if (slot != 255 && g == 0) {
        const int sg = bh * 24 + slot;
        float2* pm = (float2*)pml + sg * 128 + (w * 32 + ql);
        *pm = make_float2(m_run, l_run);
    }
    __syncthreads();

    u16* gbase;
    size_t rstride;
    if (slot == 255) {
        gbase = obuf + (rowbase + qw) * 2048 + h * 128;
        rstride = 2048;
    } else {
        const int sg = bh * 24 + slot;
        gbase = pout + (size_t)sg * 16384 + (size_t)(w * 32) * 128;
        rstride = 128;
    }
    const int eo = (lane & 15) * 8;
#pragma unroll
    for (int pass = 0; pass < 8; ++pass) {
        const int row = pass * 4 + (lane >> 4);
        bf16x8 v = *(const bf16x8*)(lO + row * 136 + eo);
        *(bf16x8*)(gbase + (size_t)row * rstride + eo) = v;
    }
}

// ---------------- merge the KV-chunk partials (qt >= 6, fan-in 2 or 3) ------
__global__ __launch_bounds__(256) void attn_merge(
    const u16* __restrict__ pout, const float* __restrict__ pml,
    u16* __restrict__ obuf)
{
    const int bid = blockIdx.x;          // 320 = j(10) x bh(32)
    const int bh = bid & 31, j = bid >> 5;
    const int qt = 6 + j;
    const int b = bh >> 4, h = bh & 15;
    const int tid = threadIdx.x;
    const int f  = (qt < 12) ? 2 : 3;
    const int sb = (qt < 12) ? (qt - 6) * 2 : 12 + (qt - 12) * 3;
    const int base = bh * 24 + sb;
    const float C2 = 0.08838834764831845f * 1.44269504088896341f;
    const int eo = (tid & 15) * 8;

#pragma unroll
    for (int pass = 0; pass < 8; ++pass) {
        const int row = pass * 16 + (tid >> 4);   // qloc 0..127
        float mv[3], lv[3], wv[3];
        float ms = -1e30f;
#pragma unroll
        for (int i = 0; i < 3; ++i) {
            if (i < f) {
                float2 ml = ((const float2*)pml)[(base + i) * 128 + row];
                mv[i] = ml.x; lv[i] = ml.y;
                ms = fmaxf(ms, ml.x);
            }
        }
        float L = 0.f;
#pragma unroll
        for (int i = 0; i < 3; ++i) {
            if (i < f) {
                wv[i] = exp2f((mv[i] - ms) * C2);
                L += lv[i] * wv[i];
            }
        }
        const float inv = 1.0f / L;

        float o[8];
#pragma unroll
        for (int e = 0; e < 8; ++e) o[e] = 0.f;
#pragma unroll
        for (int i = 0; i < 3; ++i) {
            if (i < f) {
                bf16x8 v = *(const bf16x8*)(pout + (size_t)(base + i) * 16384
                                            + (size_t)row * 128 + eo);
#pragma unroll
                for (int e = 0; e < 8; ++e) o[e] += wv[i] * bf2f((u16)v[e]);
            }
        }
        u16* orow = obuf + ((size_t)b * 2048 + qt * 128 + row) * 2048 + h * 128 + eo;
#pragma unroll
        for (int e = 0; e < 8; e += 2)
            *(u32*)(orow + e) = pack_bf2(o[e] * inv, o[e + 1] * inv);
    }
}

extern "C" void kernel_launch(void* const* d_in, const int* in_sizes, int n_in,
                              void* d_out, int out_size, void* d_ws, size_t ws_size,
                              hipStream_t stream) {
    (void)in_sizes; (void)n_in; (void)out_size; (void)ws_size;
    const float* x    = (const float*)d_in[0];
    const float* Wqkv = (const float*)d_in[1];
    const float* bqkv = (const float*)d_in[2];
    const float* Wout = (const float*)d_in[3];
    const float* bout = (const float*)d_in[4];

    char* ws = (char*)d_ws;
    u16* xb  = (u16*)ws;                        // [4096,2048] bf16, 16 MB
    u16* wqb = (u16*)(ws + (size_t)16777216);   // [6144,2048] bf16, 24 MB
    u16* qkv = (u16*)(ws + (size_t)41943040);   // [4096,6144] bf16, 48 MB
    u16* ob  = xb;   // attention out reuses xb (x dead after GEMM1)
    u16* vtb = wqb;  // V^T [32,128,2048] bf16 16 MB reuses wqb
    u16* wob = wqb;  // W_out bf16 reuses wqb again (vtb dead after attn)
    float* pml = (float*)(ws + (size_t)33554432);  // 768KB in wqb tail hole
    u16* pO  = (u16*)d_out;  // 24 MB bf16 partials: d_out is free scratch
                             // until gemm2 overwrites it

    cvt_f32_bf16<<<2048, 256, 0, stream>>>(x, xb, 8388608L / 8);
    cvt_f32_bf16<<<2048, 256, 0, stream>>>(Wqkv, wqb, 12582912L / 8);
    // gemm1: 128^2 tile, 8 waves/block (16 waves/CU), grid 32x48=1536
    gemm128_8w<<<1536, 512, 0, stream>>>(xb, wqb, bqkv, qkv, 2048, 6144, 5);
    transpose_v<<<2048, 256, 0, stream>>>(qkv, vtb);
    attn_fwd<<<960, 256, 0, stream>>>(qkv, vtb, ob, pO, pml);
    attn_merge<<<320, 256, 0, stream>>>(pO, pml, ob);
    cvt_f32_bf16<<<2048, 256, 0, stream>>>(Wout, wob, 4194304L / 8);
    gemm_nt<0><<<512, 256, 0, stream>>>(ob, wob, bout, d_out, 2048, 2048, 5);
}

// Round 17
// 298.286 us; speedup vs baseline: 1.1522x; 1.0056x over previous
//
#include <hip/hip_runtime.h>
#include <stdint.h>

typedef short bf16x8 __attribute__((ext_vector_type(8)));
typedef float f32x4 __attribute__((ext_vector_type(4)));
typedef float f32x16 __attribute__((ext_vector_type(16)));
typedef unsigned short u16;
typedef unsigned int u32;

__device__ __forceinline__ u16 f2bf(float f) {
    u32 x = __float_as_uint(f);
    x += 0x7fffu + ((x >> 16) & 1u);
    return (u16)(x >> 16);
}
__device__ __forceinline__ u32 pack_bf2(float a, float b) {
    return (u32)f2bf(a) | ((u32)f2bf(b) << 16);
}
__device__ __forceinline__ float bf2f(u16 v) {
    return __uint_as_float(((u32)v) << 16);
}

union Frag4 { u32 u[4]; bf16x8 v; };

// async global->LDS, 16B per lane; LDS dest is wave-uniform base + lane*16
__device__ __forceinline__ void gload16(const u16* g, u16* l) {
    __builtin_amdgcn_global_load_lds(
        (__attribute__((address_space(1))) void*)g,
        (__attribute__((address_space(3))) void*)l,
        16, 0, 0);
}

// ---------------- f32 -> bf16 cast, 8 elems/thread (G13: vectorized) --------
__global__ void cvt_f32_bf16(const float* __restrict__ in, u16* __restrict__ out, long n8) {
    long stride = (long)gridDim.x * blockDim.x;
    for (long i = (long)blockIdx.x * blockDim.x + threadIdx.x; i < n8; i += stride) {
        const float4* p = (const float4*)(in + i * 8);
        float4 a = p[0], b = p[1];
        uint4 o;
        o.x = pack_bf2(a.x, a.y);
        o.y = pack_bf2(a.z, a.w);
        o.z = pack_bf2(b.x, b.y);
        o.w = pack_bf2(b.z, b.w);
        ((uint4*)out)[i] = o;
    }
}

// fused dual-array cast (one launch for x + Wqkv)
__global__ void cvt2_f32_bf16(const float* __restrict__ inA, u16* __restrict__ outA, long n8A,
                              const float* __restrict__ inB, u16* __restrict__ outB, long n8B) {
    long stride = (long)gridDim.x * blockDim.x;
    const long tot = n8A + n8B;
    for (long i = (long)blockIdx.x * blockDim.x + threadIdx.x; i < tot; i += stride) {
        const float4* p;
        uint4* q;
        if (i < n8A) { p = (const float4*)(inA + i * 8);        q = (uint4*)outA + i; }
        else         { long j = i - n8A;
                       p = (const float4*)(inB + j * 8);        q = (uint4*)outB + j; }
        float4 a = p[0], b = p[1];
        uint4 o;
        o.x = pack_bf2(a.x, a.y);
        o.y = pack_bf2(a.z, a.w);
        o.z = pack_bf2(b.x, b.y);
        o.w = pack_bf2(b.z, b.w);
        *q = o;
    }
}

// ---------------- bf16 NT GEMM 128x128, 8 waves (validated round 16) --------
// 2-barrier counted-vmcnt skeleton (rounds 7-16), 64KB dbuf LDS (2 blocks/CU,
// 16 waves/CU). 512 threads: 8 waves of 64x32 output. Stage: 2 A + 2 B chunks
// per wave (4 gloads/thread/tile, vmcnt(4)). Involution swizzle both sides.
template<int OBF>
__global__ __launch_bounds__(512, 2) void gemm128_8w(
    const u16* __restrict__ A, const u16* __restrict__ B,
    const float* __restrict__ bias, void* __restrict__ out,
    int K, int ldo, int gxsh)
{
    __shared__ __align__(16) u16 lA[2 * 128 * 64];
    __shared__ __align__(16) u16 lB[2 * 128 * 64];
    const int tid  = threadIdx.x;
    const int lane = tid & 63;
    const int w    = tid >> 6;            // 0..7
    const int wm = (w >> 2) * 64;         // 2 waves in M
    const int wn = (w & 3) * 32;          // 4 waves in N

    const int nwg = gridDim.x;
    const int bid = blockIdx.x;
    const int swz = (bid & 7) * (nwg >> 3) + (bid >> 3);
    const int bm = (swz & ((1 << gxsh) - 1)) * 128;
    const int bn = (swz >> gxsh) * 128;

    const int lr = lane >> 3;
    const u32 sb = (u32)((lane & 7) * 16);
    const int NT = K >> 6;

    auto stage = [&](int bb, int k0) {
#pragma unroll
        for (int i = 0; i < 2; ++i) {
            const int c = w * 2 + i;              // chunk 0..15
            const int row = c * 8 + lr;
            const u32 col = (sb ^ ((u32)(row & 7) << 4)) >> 1;
            gload16(A + (size_t)(bm + row) * K + k0 + col, lA + bb * 8192 + c * 512);
            gload16(B + (size_t)(bn + row) * K + k0 + col, lB + bb * 8192 + c * 512);
        }
    };

    f32x4 acc[4][2];
#pragma unroll
    for (int i = 0; i < 4; ++i)
#pragma unroll
        for (int j = 0; j < 2; ++j)
#pragma unroll
            for (int r = 0; r < 4; ++r) acc[i][j][r] = 0.f;

    stage(0, 0);
    stage(1, 64);
    asm volatile("s_waitcnt vmcnt(4)" ::: "memory");
    __builtin_amdgcn_sched_barrier(0);
    __builtin_amdgcn_s_barrier();
    __builtin_amdgcn_sched_barrier(0);

    for (int t = 0; t < NT; ++t) {
        const int cur = t & 1;
        const char* pA = (const char*)(lA + cur * 8192);
        const char* pB = (const char*)(lB + cur * 8192);
#pragma unroll
        for (int kk = 0; kk < 2; ++kk) {
            bf16x8 af[4], bfr[2];
#pragma unroll
            for (int f = 0; f < 4; ++f) {
                const int m = wm + f * 16 + (lane & 15);
                const u32 byt = (u32)(kk * 64 + (lane >> 4) * 16) ^ ((u32)(m & 7) << 4);
                af[f] = *(const bf16x8*)(pA + m * 128 + byt);
            }
#pragma unroll
            for (int j = 0; j < 2; ++j) {
                const int n = wn + j * 16 + (lane & 15);
                const u32 byt = (u32)(kk * 64 + (lane >> 4) * 16) ^ ((u32)(n & 7) << 4);
                bfr[j] = *(const bf16x8*)(pB + n * 128 + byt);
            }
            __builtin_amdgcn_s_setprio(1);
#pragma unroll
            for (int i = 0; i < 4; ++i)
#pragma unroll
                for (int j = 0; j < 2; ++j)
                    acc[i][j] = __builtin_amdgcn_mfma_f32_16x16x32_bf16(af[i], bfr[j], acc[i][j], 0, 0, 0);
            __builtin_amdgcn_s_setprio(0);
        }
        __builtin_amdgcn_sched_barrier(0);
        __builtin_amdgcn_s_barrier();
        __builtin_amdgcn_sched_barrier(0);
        if (t + 2 < NT) {
            stage(cur, (t + 2) * 64);
            asm volatile("s_waitcnt vmcnt(4)" ::: "memory");
        } else {
            asm volatile("s_waitcnt vmcnt(0)" ::: "memory");
        }
        __builtin_amdgcn_sched_barrier(0);
        __builtin_amdgcn_s_barrier();
        __builtin_amdgcn_sched_barrier(0);
    }

    // epilogue: C/D layout col=lane&15, row=(lane>>4)*4+reg (m89-verified)
#pragma unroll
    for (int i = 0; i < 4; ++i) {
        int m0 = bm + wm + i * 16 + ((lane >> 4) << 2);
#pragma unroll
        for (int j = 0; j < 2; ++j) {
            int n = bn + wn + j * 16 + (lane & 15);
            float bv = bias[n];
#pragma unroll
            for (int r = 0; r < 4; ++r) {
                float v = acc[i][j][r] + bv;
                if constexpr (OBF != 0)
                    ((u16*)out)[(size_t)(m0 + r) * ldo + n] = f2bf(v);
                else
                    ((float*)out)[(size_t)(m0 + r) * ldo + n] = v;
            }
        }
    }
}

// ---------------- V transpose: vt[b,h,d,t] <- qkv[b*2048+t][4096+h*128+d] ---
__global__ __launch_bounds__(256) void transpose_v(
    const u16* __restrict__ qkv, u16* __restrict__ vt)
{
    __shared__ u16 lt[64 * 64];
    const int tid = threadIdx.x;
    const int bid = blockIdx.x;
    const int tt    = bid & 31;
    const int dtile = (bid >> 5) & 1;
    const int h     = (bid >> 6) & 15;
    const int b     = bid >> 10;
    const u16* src = qkv + ((size_t)b * 2048 + tt * 64) * 6144 + 4096 + h * 128 + dtile * 64;

    const int r = tid >> 2, ce = (tid & 3) * 16;
    uint4 a0 = *(const uint4*)(src + (size_t)r * 6144 + ce);
    uint4 a1 = *(const uint4*)(src + (size_t)r * 6144 + ce + 8);
    const u32 swz = (u32)((r & 7) << 4);
    *(uint4*)((char*)lt + r * 128 + (((u32)(ce * 2)) ^ swz)) = a0;
    *(uint4*)((char*)lt + r * 128 + (((u32)(ce * 2 + 16)) ^ swz)) = a1;
    __syncthreads();

    const int d = tid >> 2;
    u16* dst = vt + ((size_t)(b * 16 + h) * 128 + dtile * 64 + d) * 2048 + tt * 64;
#pragma unroll
    for (int it = 0; it < 2; ++it) {
        const int t0 = (tid & 3) * 8 + it * 32;
        union { u16 hh[8]; uint4 q4; } u;
#pragma unroll
        for (int uu = 0; uu < 8; ++uu) {
            int trow = t0 + uu;
            u32 byt = (u32)(trow * 128) + (((u32)(d * 2)) ^ ((u32)((trow & 7) << 4)));
            u.hh[uu] = *(const u16*)((const char*)lt + byt);
        }
        *(uint4*)(dst + t0) = u.q4;
    }
}

// ---------------- causal flash attention (round-13 validated) ---------------
__constant__ unsigned char QT_TAB[30] = {11,11, 5,15,15,15,10,10,14,14,14, 9, 9, 4,13,13,13,12,12,12, 8, 8, 7, 7, 3, 6, 6, 2, 1, 0};
__constant__ unsigned char TLO_TAB[30]= { 0,24, 0, 0,22,43, 0,22, 0,20,40, 0,20, 0, 0,19,38, 0,18,36, 0,18, 0,16, 0, 0,14, 0, 0, 0};
__constant__ unsigned char THI_TAB[30]= {24,48,24,22,43,64,22,44,20,40,60,20,40,20,19,38,56,18,36,52,18,36,16,32,16,14,28,12, 8, 4};
__constant__ unsigned char SL_TAB[30] = {10,11,255,21,22,23, 8, 9,18,19,20, 6, 7,255,15,16,17,12,13,14, 4, 5, 2, 3,255, 0, 1,255,255,255};

__global__ __launch_bounds__(256) void attn_fwd(
    const u16* __restrict__ qkv, const u16* __restrict__ vt,
    u16* __restrict__ obuf, u16* __restrict__ pout, float* __restrict__ pml)
{
    __shared__ __align__(16) u16 lS[17408];
    const int tid  = threadIdx.x;
    const int lane = tid & 63;
    const int w    = tid >> 6;
    const int g    = lane >> 5;
    const int ql   = lane & 31;

    const int bid  = blockIdx.x;
    const int item = bid >> 5;
    const int bh   = bid & 31;
    const int qt   = QT_TAB[item];
    const int slot = SL_TAB[item];
    const int t_lo = TLO_TAB[item];
    const int t_hi = THI_TAB[item];
    const int b = bh >> 4, h = bh & 15;
    const size_t rowbase = (size_t)b * 2048;
    const int qb = qt * 128;
    const int qw = qb + w * 32;
    const int q  = qw + ql;

    const u16* Khead = qkv + rowbase * 6144 + 2048 + h * 128;  // ld 6144
    const u16* Vth   = vt + (size_t)bh * 128 * 2048;           // Vt[d][t]

    bf16x8 qf[8];
    {
        const u16* qrow = qkv + (rowbase + q) * 6144 + h * 128;
#pragma unroll
        for (int ch = 0; ch < 8; ++ch)
            qf[ch] = *(const bf16x8*)(qrow + ch * 16 + g * 8);
    }

    f32x16 acc[4];
#pragma unroll
    for (int dt = 0; dt < 4; ++dt)
#pragma unroll
        for (int r = 0; r < 16; ++r) acc[dt][r] = 0.f;

    float m_run = -1e30f, l_run = 0.f;
    const float C2 = 0.08838834764831845f * 1.44269504088896341f; // scale*log2e

    auto stage = [&](int bb, int t) {
        const int kb = t * 32;
#pragma unroll
        for (int i = 0; i < 2; ++i) {
            const int c = w * 2 + i;
            const int kr = c * 4 + (lane >> 4);
            const u32 kcol = (((u32)((lane & 15) * 16)) ^ ((u32)(kr & 7) << 4)) >> 1;
            gload16(Khead + (size_t)(kb + kr) * 6144 + kcol,
                    lS + bb * 4096 + c * 512);
            const int vr = c * 16 + (lane >> 2);
            const u32 vcol = (((u32)((lane & 3) * 16)) ^ ((u32)(vr & 3) << 4)) >> 1;
            gload16(Vth + (size_t)vr * 2048 + kb + vcol,
                    lS + 8192 + bb * 4096 + c * 512);
        }
    };

    stage(0, t_lo);
    __syncthreads();
    int buf = 0;

    for (int t = t_lo; t < t_hi; ++t) {
        const int kb = t * 32;
        if (t + 1 < t_hi) stage(buf ^ 1, t + 1);

        if (kb <= qw + 31) {
            const char* lKb = (const char*)(lS + buf * 4096);
            const char* lVb = (const char*)(lS + 8192 + buf * 4096);
            const bool diag = (kb == qw);

            bf16x8 kf[8];
            const u32 ksw = ((u32)ql & 7) << 4;
#pragma unroll
            for (int ch = 0; ch < 8; ++ch)
                kf[ch] = *(const bf16x8*)(lKb + ql * 256 + (((u32)(ch * 32 + g * 16)) ^ ksw));

            f32x16 s_;
#pragma unroll
            for (int r = 0; r < 16; ++r) s_[r] = 0.f;
            __builtin_amdgcn_s_setprio(1);
#pragma unroll
            for (int ch = 0; ch < 8; ++ch)
                s_ = __builtin_amdgcn_mfma_f32_32x32x16_bf16(kf[ch], qf[ch], s_, 0, 0, 0);
            __builtin_amdgcn_s_setprio(0);

            float p[16];
            float tmax = -1e30f;
#pragma unroll
            for (int r = 0; r < 16; ++r) {
                int crow = (r & 3) + 8 * (r >> 2) + 4 * g;
                float v = s_[r];
                if (diag && (crow > ql)) v = -1e30f;   // causal mask
                p[r] = v;
                tmax = fmaxf(tmax, v);
            }
            tmax = fmaxf(tmax, __shfl_xor(tmax, 32));
            if (!__all(tmax <= m_run + 8.0f)) {
                float mnew  = fmaxf(m_run, tmax);
                float alpha = exp2f((m_run - mnew) * C2);
#pragma unroll
                for (int dt = 0; dt < 4; ++dt) acc[dt] = acc[dt] * alpha;
                l_run *= alpha;
                m_run = mnew;
            }
            float ssum = 0.f;
#pragma unroll
            for (int r = 0; r < 16; ++r) {
                float e = exp2f((p[r] - m_run) * C2);
                p[r] = e;
                ssum += e;
            }
            ssum += __shfl_xor(ssum, 32);
            l_run += ssum;

            u32 wb[8], sw[8];
#pragma unroll
            for (int j = 0; j < 8; ++j) wb[j] = pack_bf2(p[2 * j], p[2 * j + 1]);
#pragma unroll
            for (int j = 0; j < 8; ++j) sw[j] = __shfl_xor(wb[j], 32);
            Frag4 pf0, pf1;
#pragma unroll
            for (int u = 0; u < 4; ++u) {
                const bool own = (g == (u >> 1));
                pf0.u[u] = own ? wb[2 * g + (u & 1)]     : sw[2 * g + (u & 1)];
                pf1.u[u] = own ? wb[4 + 2 * g + (u & 1)] : sw[4 + 2 * g + (u & 1)];
            }

            __builtin_amdgcn_s_setprio(1);
#pragma unroll
            for (int dt = 0; dt < 4; ++dt) {
                const u32 vrow = (u32)(dt * 32 + ql);
                const u32 vsw = (vrow & 3) << 4;
                bf16x8 v0 = *(const bf16x8*)(lVb + vrow * 64 + (((u32)(g * 16)) ^ vsw));
                bf16x8 v1 = *(const bf16x8*)(lVb + vrow * 64 + (((u32)(32 + g * 16)) ^ vsw));
                acc[dt] = __builtin_amdgcn_mfma_f32_32x32x16_bf16(v0, pf0.v, acc[dt], 0, 0, 0);
                acc[dt] = __builtin_amdgcn_mfma_f32_32x32x16_bf16(v1, pf1.v, acc[dt], 0, 0, 0);
            }
            __builtin_amdgcn_s_setprio(0);
        }
        __syncthreads();
        buf ^= 1;
    }

    // epilogue via LDS for coalesced global stores (validated round 13)
    const float scale = (slot == 255) ? (1.0f / l_run) : 1.0f;
    u16* lO = lS + w * 4352;
#pragma unroll
    for (int dt = 0; dt < 4; ++dt) {
#pragma unroll
        for (int rr = 0; rr < 4; ++rr) {
            int d0 = dt * 32 + rr * 8 + g * 4;
            int r0 = rr * 4;
            u32* dst = (u32*)(lO + ql * 136 + d0);
            dst[0] = pack_bf2(acc[dt][r0] * scale,     acc[dt][r0 + 1] * scale);
            dst[1] = pack_bf2(acc[dt][r0 + 2] * scale, acc[dt][r0 + 3] * scale);
        }
    }
    if (slot != 255 && g == 0) {
        const int sg = bh * 24 + slot;
        float2* pm = (float2*)pml + sg * 128 + (w * 32 + ql);
        *pm = make_float2(m_run, l_run);
    }
    __syncthreads();

    u16* gbase;
    size_t rstride;
    if (slot == 255) {
        gbase = obuf + (rowbase + qw) * 2048 + h * 128;
        rstride = 2048;
    } else {
        const int sg = bh * 24 + slot;
        gbase = pout + (size_t)sg * 16384 + (size_t)(w * 32) * 128;
        rstride = 128;
    }
    const int eo = (lane & 15) * 8;
#pragma unroll
    for (int pass = 0; pass < 8; ++pass) {
        const int row = pass * 4 + (lane >> 4);
        bf16x8 v = *(const bf16x8*)(lO + row * 136 + eo);
        *(bf16x8*)(gbase + (size_t)row * rstride + eo) = v;
    }
}

// ---------------- merge the KV-chunk partials (qt >= 6, fan-in 2 or 3) ------
__global__ __launch_bounds__(256) void attn_merge(
    const u16* __restrict__ pout, const float* __restrict__ pml,
    u16* __restrict__ obuf)
{
    const int bid = blockIdx.x;          // 320 = j(10) x bh(32)
    const int bh = bid & 31, j = bid >> 5;
    const int qt = 6 + j;
    const int b = bh >> 4, h = bh & 15;
    const int tid = threadIdx.x;
    const int f  = (qt < 12) ? 2 : 3;
    const int sb = (qt < 12) ? (qt - 6) * 2 : 12 + (qt - 12) * 3;
    const int base = bh * 24 + sb;
    const float C2 = 0.08838834764831845f * 1.44269504088896341f;
    const int eo = (tid & 15) * 8;

#pragma unroll
    for (int pass = 0; pass < 8; ++pass) {
        const int row = pass * 16 + (tid >> 4);   // qloc 0..127
        float mv[3], lv[3], wv[3];
        float ms = -1e30f;
#pragma unroll
        for (int i = 0; i < 3; ++i) {
            if (i < f) {
                float2 ml = ((const float2*)pml)[(base + i) * 128 + row];
                mv[i] = ml.x; lv[i] = ml.y;
                ms = fmaxf(ms, ml.x);
            }
        }
        float L = 0.f;
#pragma unroll
        for (int i = 0; i < 3; ++i) {
            if (i < f) {
                wv[i] = exp2f((mv[i] - ms) * C2);
                L += lv[i] * wv[i];
            }
        }
        const float inv = 1.0f / L;

        float o[8];
#pragma unroll
        for (int e = 0; e < 8; ++e) o[e] = 0.f;
#pragma unroll
        for (int i = 0; i < 3; ++i) {
            if (i < f) {
                bf16x8 v = *(const bf16x8*)(pout + (size_t)(base + i) * 16384
                                            + (size_t)row * 128 + eo);
#pragma unroll
                for (int e = 0; e < 8; ++e) o[e] += wv[i] * bf2f((u16)v[e]);
            }
        }
        u16* orow = obuf + ((size_t)b * 2048 + qt * 128 + row) * 2048 + h * 128 + eo;
#pragma unroll
        for (int e = 0; e < 8; e += 2)
            *(u32*)(orow + e) = pack_bf2(o[e] * inv, o[e + 1] * inv);
    }
}

extern "C" void kernel_launch(void* const* d_in, const int* in_sizes, int n_in,
                              void* d_out, int out_size, void* d_ws, size_t ws_size,
                              hipStream_t stream) {
    (void)in_sizes; (void)n_in; (void)out_size; (void)ws_size;
    const float* x    = (const float*)d_in[0];
    const float* Wqkv = (const float*)d_in[1];
    const float* bqkv = (const float*)d_in[2];
    const float* Wout = (const float*)d_in[3];
    const float* bout = (const float*)d_in[4];

    char* ws = (char*)d_ws;
    u16* xb  = (u16*)ws;                        // [4096,2048] bf16, 16 MB
    u16* wqb = (u16*)(ws + (size_t)16777216);   // [6144,2048] bf16, 24 MB
    u16* qkv = (u16*)(ws + (size_t)41943040);   // [4096,6144] bf16, 48 MB
    u16* ob  = xb;   // attention out reuses xb (x dead after GEMM1)
    u16* vtb = wqb;  // V^T [32,128,2048] bf16 16 MB reuses wqb
    u16* wob = wqb;  // W_out bf16 reuses wqb again (vtb dead after attn)
    float* pml = (float*)(ws + (size_t)33554432);  // 768KB in wqb tail hole
    u16* pO  = (u16*)d_out;  // 24 MB bf16 partials: d_out is free scratch
                             // until gemm2 overwrites it

    // fused x + Wqkv cast (one launch)
    cvt2_f32_bf16<<<2048, 256, 0, stream>>>(x, xb, 8388608L / 8,
                                            Wqkv, wqb, 12582912L / 8);
    // gemm1: 128^2 tile, 8 waves/block, grid 32x48=1536, bf16 out
    gemm128_8w<1><<<1536, 512, 0, stream>>>(xb, wqb, bqkv, qkv, 2048, 6144, 5);
    transpose_v<<<2048, 256, 0, stream>>>(qkv, vtb);
    attn_fwd<<<960, 256, 0, stream>>>(qkv, vtb, ob, pO, pml);
    attn_merge<<<320, 256, 0, stream>>>(pO, pml, ob);
    cvt_f32_bf16<<<2048, 256, 0, stream>>>(Wout, wob, 4194304L / 8);
    // gemm2: same 8-wave structure, f32 out, grid 32x16=512
    gemm128_8w<0><<<512, 512, 0, stream>>>(ob, wob, bout, d_out, 2048, 2048, 5);
}

// Round 18
// 297.533 us; speedup vs baseline: 1.1552x; 1.0025x over previous
//
#include <hip/hip_runtime.h>
#include <stdint.h>

typedef short bf16x8 __attribute__((ext_vector_type(8)));
typedef float f32x4 __attribute__((ext_vector_type(4)));
typedef float f32x16 __attribute__((ext_vector_type(16)));
typedef unsigned short u16;
typedef unsigned int u32;

__device__ __forceinline__ u16 f2bf(float f) {
    u32 x = __float_as_uint(f);
    x += 0x7fffu + ((x >> 16) & 1u);
    return (u16)(x >> 16);
}
__device__ __forceinline__ u32 pack_bf2(float a, float b) {
    return (u32)f2bf(a) | ((u32)f2bf(b) << 16);
}
__device__ __forceinline__ float bf2f(u16 v) {
    return __uint_as_float(((u32)v) << 16);
}

union Frag4 { u32 u[4]; bf16x8 v; };

// async global->LDS, 16B per lane; LDS dest is wave-uniform base + lane*16
__device__ __forceinline__ void gload16(const u16* g, u16* l) {
    __builtin_amdgcn_global_load_lds(
        (__attribute__((address_space(1))) void*)g,
        (__attribute__((address_space(3))) void*)l,
        16, 0, 0);
}

// ---------------- f32 -> bf16 cast, 8 elems/thread (G13: vectorized) --------
__global__ void cvt_f32_bf16(const float* __restrict__ in, u16* __restrict__ out, long n8) {
    long stride = (long)gridDim.x * blockDim.x;
    for (long i = (long)blockIdx.x * blockDim.x + threadIdx.x; i < n8; i += stride) {
        const float4* p = (const float4*)(in + i * 8);
        float4 a = p[0], b = p[1];
        uint4 o;
        o.x = pack_bf2(a.x, a.y);
        o.y = pack_bf2(a.z, a.w);
        o.z = pack_bf2(b.x, b.y);
        o.w = pack_bf2(b.z, b.w);
        ((uint4*)out)[i] = o;
    }
}

// fused dual-array cast (one launch for x + Wqkv)
__global__ void cvt2_f32_bf16(const float* __restrict__ inA, u16* __restrict__ outA, long n8A,
                              const float* __restrict__ inB, u16* __restrict__ outB, long n8B) {
    long stride = (long)gridDim.x * blockDim.x;
    const long tot = n8A + n8B;
    for (long i = (long)blockIdx.x * blockDim.x + threadIdx.x; i < tot; i += stride) {
        const float4* p;
        uint4* q;
        if (i < n8A) { p = (const float4*)(inA + i * 8);        q = (uint4*)outA + i; }
        else         { long j = i - n8A;
                       p = (const float4*)(inB + j * 8);        q = (uint4*)outB + j; }
        float4 a = p[0], b = p[1];
        uint4 o;
        o.x = pack_bf2(a.x, a.y);
        o.y = pack_bf2(a.z, a.w);
        o.z = pack_bf2(b.x, b.y);
        o.w = pack_bf2(b.z, b.w);
        *q = o;
    }
}

// ---------------- bf16 NT GEMM 128x128, 8 waves, T3-minimum 1-barrier -------
// Guide-blessed "minimum 2-phase" (T3+T4 recipe): per K-tile
//   { STAGE(buf^1, t+1) ; ds_read(buf)+MFMA ; vmcnt(0) ; barrier }
// One barrier/tile (vs two in the m97-style loop). Stage issued BEFORE
// compute so the 4 loads/wave span the whole MFMA phase. Per-wave FIFO:
// each wave's vmcnt(0) drains its own loads pre-barrier; post-barrier all
// reads of buf are done so next iter may stage into it. 64KB dbuf LDS,
// 2 blocks/CU, 16 waves/CU, involution swizzle both sides (rule #21).
template<int OBF>
__global__ __launch_bounds__(512, 2) void gemm128_1b(
    const u16* __restrict__ A, const u16* __restrict__ B,
    const float* __restrict__ bias, void* __restrict__ out,
    int K, int ldo, int gxsh)
{
    __shared__ __align__(16) u16 lA[2 * 128 * 64];
    __shared__ __align__(16) u16 lB[2 * 128 * 64];
    const int tid  = threadIdx.x;
    const int lane = tid & 63;
    const int w    = tid >> 6;            // 0..7
    const int wm = (w >> 2) * 64;         // 2 waves in M
    const int wn = (w & 3) * 32;          // 4 waves in N

    const int nwg = gridDim.x;
    const int bid = blockIdx.x;
    const int swz = (bid & 7) * (nwg >> 3) + (bid >> 3);
    const int bm = (swz & ((1 << gxsh) - 1)) * 128;
    const int bn = (swz >> gxsh) * 128;

    const int lr = lane >> 3;
    const u32 sb = (u32)((lane & 7) * 16);
    const int NT = K >> 6;

    auto stage = [&](int bb, int k0) {
#pragma unroll
        for (int i = 0; i < 2; ++i) {
            const int c = w * 2 + i;              // chunk 0..15
            const int row = c * 8 + lr;
            const u32 col = (sb ^ ((u32)(row & 7) << 4)) >> 1;
            gload16(A + (size_t)(bm + row) * K + k0 + col, lA + bb * 8192 + c * 512);
            gload16(B + (size_t)(bn + row) * K + k0 + col, lB + bb * 8192 + c * 512);
        }
    };

    f32x4 acc[4][2];
#pragma unroll
    for (int i = 0; i < 4; ++i)
#pragma unroll
        for (int j = 0; j < 2; ++j)
#pragma unroll
            for (int r = 0; r < 4; ++r) acc[i][j][r] = 0.f;

    // prologue: STAGE(buf0, t=0); vmcnt(0); barrier
    stage(0, 0);
    asm volatile("s_waitcnt vmcnt(0)" ::: "memory");
    __builtin_amdgcn_sched_barrier(0);
    __builtin_amdgcn_s_barrier();
    __builtin_amdgcn_sched_barrier(0);

    int cur = 0;
    for (int t = 0; t < NT; ++t) {
        // issue next-tile loads first (they span the compute phase)
        if (t + 1 < NT) stage(cur ^ 1, (t + 1) * 64);
        __builtin_amdgcn_sched_barrier(0);

        const char* pA = (const char*)(lA + cur * 8192);
        const char* pB = (const char*)(lB + cur * 8192);
#pragma unroll
        for (int kk = 0; kk < 2; ++kk) {
            bf16x8 af[4], bfr[2];
#pragma unroll
            for (int f = 0; f < 4; ++f) {
                const int m = wm + f * 16 + (lane & 15);
                const u32 byt = (u32)(kk * 64 + (lane >> 4) * 16) ^ ((u32)(m & 7) << 4);
                af[f] = *(const bf16x8*)(pA + m * 128 + byt);
            }
#pragma unroll
            for (int j = 0; j < 2; ++j) {
                const int n = wn + j * 16 + (lane & 15);
                const u32 byt = (u32)(kk * 64 + (lane >> 4) * 16) ^ ((u32)(n & 7) << 4);
                bfr[j] = *(const bf16x8*)(pB + n * 128 + byt);
            }
            __builtin_amdgcn_s_setprio(1);
#pragma unroll
            for (int i = 0; i < 4; ++i)
#pragma unroll
                for (int j = 0; j < 2; ++j)
                    acc[i][j] = __builtin_amdgcn_mfma_f32_16x16x32_bf16(af[i], bfr[j], acc[i][j], 0, 0, 0);
            __builtin_amdgcn_s_setprio(0);
        }
        // single per-tile sync: drain own stage loads, then barrier
        asm volatile("s_waitcnt vmcnt(0)" ::: "memory");
        __builtin_amdgcn_sched_barrier(0);
        __builtin_amdgcn_s_barrier();
        __builtin_amdgcn_sched_barrier(0);
        cur ^= 1;
    }

    // epilogue: C/D layout col=lane&15, row=(lane>>4)*4+reg (m89-verified)
#pragma unroll
    for (int i = 0; i < 4; ++i) {
        int m0 = bm + wm + i * 16 + ((lane >> 4) << 2);
#pragma unroll
        for (int j = 0; j < 2; ++j) {
            int n = bn + wn + j * 16 + (lane & 15);
            float bv = bias[n];
#pragma unroll
            for (int r = 0; r < 4; ++r) {
                float v = acc[i][j][r] + bv;
                if constexpr (OBF != 0)
                    ((u16*)out)[(size_t)(m0 + r) * ldo + n] = f2bf(v);
                else
                    ((float*)out)[(size_t)(m0 + r) * ldo + n] = v;
            }
        }
    }
}

// ---------------- bf16 NT GEMM 128x128, 8 waves (validated round 16) --------
template<int OBF>
__global__ __launch_bounds__(512, 2) void gemm128_8w(
    const u16* __restrict__ A, const u16* __restrict__ B,
    const float* __restrict__ bias, void* __restrict__ out,
    int K, int ldo, int gxsh)
{
    __shared__ __align__(16) u16 lA[2 * 128 * 64];
    __shared__ __align__(16) u16 lB[2 * 128 * 64];
    const int tid  = threadIdx.x;
    const int lane = tid & 63;
    const int w    = tid >> 6;            // 0..7
    const int wm = (w >> 2) * 64;         // 2 waves in M
    const int wn = (w & 3) * 32;          // 4 waves in N

    const int nwg = gridDim.x;
    const int bid = blockIdx.x;
    const int swz = (bid & 7) * (nwg >> 3) + (bid >> 3);
    const int bm = (swz & ((1 << gxsh) - 1)) * 128;
    const int bn = (swz >> gxsh) * 128;

    const int lr = lane >> 3;
    const u32 sb = (u32)((lane & 7) * 16);
    const int NT = K >> 6;

    auto stage = [&](int bb, int k0) {
#pragma unroll
        for (int i = 0; i < 2; ++i) {
            const int c = w * 2 + i;              // chunk 0..15
            const int row = c * 8 + lr;
            const u32 col = (sb ^ ((u32)(row & 7) << 4)) >> 1;
            gload16(A + (size_t)(bm + row) * K + k0 + col, lA + bb * 8192 + c * 512);
            gload16(B + (size_t)(bn + row) * K + k0 + col, lB + bb * 8192 + c * 512);
        }
    };

    f32x4 acc[4][2];
#pragma unroll
    for (int i = 0; i < 4; ++i)
#pragma unroll
        for (int j = 0; j < 2; ++j)
#pragma unroll
            for (int r = 0; r < 4; ++r) acc[i][j][r] = 0.f;

    stage(0, 0);
    stage(1, 64);
    asm volatile("s_waitcnt vmcnt(4)" ::: "memory");
    __builtin_amdgcn_sched_barrier(0);
    __builtin_amdgcn_s_barrier();
    __builtin_amdgcn_sched_barrier(0);

    for (int t = 0; t < NT; ++t) {
        const int cur = t & 1;
        const char* pA = (const char*)(lA + cur * 8192);
        const char* pB = (const char*)(lB + cur * 8192);
#pragma unroll
        for (int kk = 0; kk < 2; ++kk) {
            bf16x8 af[4], bfr[2];
#pragma unroll
            for (int f = 0; f < 4; ++f) {
                const int m = wm + f * 16 + (lane & 15);
                const u32 byt = (u32)(kk * 64 + (lane >> 4) * 16) ^ ((u32)(m & 7) << 4);
                af[f] = *(const bf16x8*)(pA + m * 128 + byt);
            }
#pragma unroll
            for (int j = 0; j < 2; ++j) {
                const int n = wn + j * 16 + (lane & 15);
                const u32 byt = (u32)(kk * 64 + (lane >> 4) * 16) ^ ((u32)(n & 7) << 4);
                bfr[j] = *(const bf16x8*)(pB + n * 128 + byt);
            }
            __builtin_amdgcn_s_setprio(1);
#pragma unroll
            for (int i = 0; i < 4; ++i)
#pragma unroll
                for (int j = 0; j < 2; ++j)
                    acc[i][j] = __builtin_amdgcn_mfma_f32_16x16x32_bf16(af[i], bfr[j], acc[i][j], 0, 0, 0);
            __builtin_amdgcn_s_setprio(0);
        }
        __builtin_amdgcn_sched_barrier(0);
        __builtin_amdgcn_s_barrier();
        __builtin_amdgcn_sched_barrier(0);
        if (t + 2 < NT) {
            stage(cur, (t + 2) * 64);
            asm volatile("s_waitcnt vmcnt(4)" ::: "memory");
        } else {
            asm volatile("s_waitcnt vmcnt(0)" ::: "memory");
        }
        __builtin_amdgcn_sched_barrier(0);
        __builtin_amdgcn_s_barrier();
        __builtin_amdgcn_sched_barrier(0);
    }

#pragma unroll
    for (int i = 0; i < 4; ++i) {
        int m0 = bm + wm + i * 16 + ((lane >> 4) << 2);
#pragma unroll
        for (int j = 0; j < 2; ++j) {
            int n = bn + wn + j * 16 + (lane & 15);
            float bv = bias[n];
#pragma unroll
            for (int r = 0; r < 4; ++r) {
                float v = acc[i][j][r] + bv;
                if constexpr (OBF != 0)
                    ((u16*)out)[(size_t)(m0 + r) * ldo + n] = f2bf(v);
                else
                    ((float*)out)[(size_t)(m0 + r) * ldo + n] = v;
            }
        }
    }
}

// ---------------- V transpose: vt[b,h,d,t] <- qkv[b*2048+t][4096+h*128+d] ---
__global__ __launch_bounds__(256) void transpose_v(
    const u16* __restrict__ qkv, u16* __restrict__ vt)
{
    __shared__ u16 lt[64 * 64];
    const int tid = threadIdx.x;
    const int bid = blockIdx.x;
    const int tt    = bid & 31;
    const int dtile = (bid >> 5) & 1;
    const int h     = (bid >> 6) & 15;
    const int b     = bid >> 10;
    const u16* src = qkv + ((size_t)b * 2048 + tt * 64) * 6144 + 4096 + h * 128 + dtile * 64;

    const int r = tid >> 2, ce = (tid & 3) * 16;
    uint4 a0 = *(const uint4*)(src + (size_t)r * 6144 + ce);
    uint4 a1 = *(const uint4*)(src + (size_t)r * 6144 + ce + 8);
    const u32 swz = (u32)((r & 7) << 4);
    *(uint4*)((char*)lt + r * 128 + (((u32)(ce * 2)) ^ swz)) = a0;
    *(uint4*)((char*)lt + r * 128 + (((u32)(ce * 2 + 16)) ^ swz)) = a1;
    __syncthreads();

    const int d = tid >> 2;
    u16* dst = vt + ((size_t)(b * 16 + h) * 128 + dtile * 64 + d) * 2048 + tt * 64;
#pragma unroll
    for (int it = 0; it < 2; ++it) {
        const int t0 = (tid & 3) * 8 + it * 32;
        union { u16 hh[8]; uint4 q4; } u;
#pragma unroll
        for (int uu = 0; uu < 8; ++uu) {
            int trow = t0 + uu;
            u32 byt = (u32)(trow * 128) + (((u32)(d * 2)) ^ ((u32)((trow & 7) << 4)));
            u.hh[uu] = *(const u16*)((const char*)lt + byt);
        }
        *(uint4*)(dst + t0) = u.q4;
    }
}

// ---------------- causal flash attention (round-13 validated) ---------------
__constant__ unsigned char QT_TAB[30] = {11,11, 5,15,15,15,10,10,14,14,14, 9, 9, 4,13,13,13,12,12,12, 8, 8, 7, 7, 3, 6, 6, 2, 1, 0};
__constant__ unsigned char TLO_TAB[30]= { 0,24, 0, 0,22,43, 0,22, 0,20,40, 0,20, 0, 0,19,38, 0,18,36, 0,18, 0,16, 0, 0,14, 0, 0, 0};
__constant__ unsigned char THI_TAB[30]= {24,48,24,22,43,64,22,44,20,40,60,20,40,20,19,38,56,18,36,52,18,36,16,32,16,14,28,12, 8, 4};
__constant__ unsigned char SL_TAB[30] = {10,11,255,21,22,23, 8, 9,18,19,20, 6, 7,255,15,16,17,12,13,14, 4, 5, 2, 3,255, 0, 1,255,255,255};

__global__ __launch_bounds__(256) void attn_fwd(
    const u16* __restrict__ qkv, const u16* __restrict__ vt,
    u16* __restrict__ obuf, u16* __restrict__ pout, float* __restrict__ pml)
{
    __shared__ __align__(16) u16 lS[17408];
    const int tid  = threadIdx.x;
    const int lane = tid & 63;
    const int w    = tid >> 6;
    const int g    = lane >> 5;
    const int ql   = lane & 31;

    const int bid  = blockIdx.x;
    const int item = bid >> 5;
    const int bh   = bid & 31;
    const int qt   = QT_TAB[item];
    const int slot = SL_TAB[item];
    const int t_lo = TLO_TAB[item];
    const int t_hi = THI_TAB[item];
    const int b = bh >> 4, h = bh & 15;
    const size_t rowbase = (size_t)b * 2048;
    const int qb = qt * 128;
    const int qw = qb + w * 32;
    const int q  = qw + ql;

    const u16* Khead = qkv + rowbase * 6144 + 2048 + h * 128;  // ld 6144
    const u16* Vth   = vt + (size_t)bh * 128 * 2048;           // Vt[d][t]

    bf16x8 qf[8];
    {
        const u16* qrow = qkv + (rowbase + q) * 6144 + h * 128;
#pragma unroll
        for (int ch = 0; ch < 8; ++ch)
            qf[ch] = *(const bf16x8*)(qrow + ch * 16 + g * 8);
    }

    f32x16 acc[4];
#pragma unroll
    for (int dt = 0; dt < 4; ++dt)
#pragma unroll
        for (int r = 0; r < 16; ++r) acc[dt][r] = 0.f;

    float m_run = -1e30f, l_run = 0.f;
    const float C2 = 0.08838834764831845f * 1.44269504088896341f; // scale*log2e

    auto stage = [&](int bb, int t) {
        const int kb = t * 32;
#pragma unroll
        for (int i = 0; i < 2; ++i) {
            const int c = w * 2 + i;
            const int kr = c * 4 + (lane >> 4);
            const u32 kcol = (((u32)((lane & 15) * 16)) ^ ((u32)(kr & 7) << 4)) >> 1;
            gload16(Khead + (size_t)(kb + kr) * 6144 + kcol,
                    lS + bb * 4096 + c * 512);
            const int vr = c * 16 + (lane >> 2);
            const u32 vcol = (((u32)((lane & 3) * 16)) ^ ((u32)(vr & 3) << 4)) >> 1;
            gload16(Vth + (size_t)vr * 2048 + kb + vcol,
                    lS + 8192 + bb * 4096 + c * 512);
        }
    };

    stage(0, t_lo);
    __syncthreads();
    int buf = 0;

    for (int t = t_lo; t < t_hi; ++t) {
        const int kb = t * 32;
        if (t + 1 < t_hi) stage(buf ^ 1, t + 1);

        if (kb <= qw + 31) {
            const char* lKb = (const char*)(lS + buf * 4096);
            const char* lVb = (const char*)(lS + 8192 + buf * 4096);
            const bool diag = (kb == qw);

            bf16x8 kf[8];
            const u32 ksw = ((u32)ql & 7) << 4;
#pragma unroll
            for (int ch = 0; ch < 8; ++ch)
                kf[ch] = *(const bf16x8*)(lKb + ql * 256 + (((u32)(ch * 32 + g * 16)) ^ ksw));

            f32x16 s_;
#pragma unroll
            for (int r = 0; r < 16; ++r) s_[r] = 0.f;
            __builtin_amdgcn_s_setprio(1);
#pragma unroll
            for (int ch = 0; ch < 8; ++ch)
                s_ = __builtin_amdgcn_mfma_f32_32x32x16_bf16(kf[ch], qf[ch], s_, 0, 0, 0);
            __builtin_amdgcn_s_setprio(0);

            float p[16];
            float tmax = -1e30f;
#pragma unroll
            for (int r = 0; r < 16; ++r) {
                int crow = (r & 3) + 8 * (r >> 2) + 4 * g;
                float v = s_[r];
                if (diag && (crow > ql)) v = -1e30f;   // causal mask
                p[r] = v;
                tmax = fmaxf(tmax, v);
            }
            tmax = fmaxf(tmax, __shfl_xor(tmax, 32));
            if (!__all(tmax <= m_run + 8.0f)) {
                float mnew  = fmaxf(m_run, tmax);
                float alpha = exp2f((m_run - mnew) * C2);
#pragma unroll
                for (int dt = 0; dt < 4; ++dt) acc[dt] = acc[dt] * alpha;
                l_run *= alpha;
                m_run = mnew;
            }
            float ssum = 0.f;
#pragma unroll
            for (int r = 0; r < 16; ++r) {
                float e = exp2f((p[r] - m_run) * C2);
                p[r] = e;
                ssum += e;
            }
            ssum += __shfl_xor(ssum, 32);
            l_run += ssum;

            u32 wb[8], sw[8];
#pragma unroll
            for (int j = 0; j < 8; ++j) wb[j] = pack_bf2(p[2 * j], p[2 * j + 1]);
#pragma unroll
            for (int j = 0; j < 8; ++j) sw[j] = __shfl_xor(wb[j], 32);
            Frag4 pf0, pf1;
#pragma unroll
            for (int u = 0; u < 4; ++u) {
                const bool own = (g == (u >> 1));
                pf0.u[u] = own ? wb[2 * g + (u & 1)]     : sw[2 * g + (u & 1)];
                pf1.u[u] = own ? wb[4 + 2 * g + (u & 1)] : sw[4 + 2 * g + (u & 1)];
            }

            __builtin_amdgcn_s_setprio(1);
#pragma unroll
            for (int dt = 0; dt < 4; ++dt) {
                const u32 vrow = (u32)(dt * 32 + ql);
                const u32 vsw = (vrow & 3) << 4;
                bf16x8 v0 = *(const bf16x8*)(lVb + vrow * 64 + (((u32)(g * 16)) ^ vsw));
                bf16x8 v1 = *(const bf16x8*)(lVb + vrow * 64 + (((u32)(32 + g * 16)) ^ vsw));
                acc[dt] = __builtin_amdgcn_mfma_f32_32x32x16_bf16(v0, pf0.v, acc[dt], 0, 0, 0);
                acc[dt] = __builtin_amdgcn_mfma_f32_32x32x16_bf16(v1, pf1.v, acc[dt], 0, 0, 0);
            }
            __builtin_amdgcn_s_setprio(0);
        }
        __syncthreads();
        buf ^= 1;
    }

    // epilogue via LDS for coalesced global stores (validated round 13)
    const float scale = (slot == 255) ? (1.0f / l_run) : 1.0f;
    u16* lO = lS + w * 4352;
#pragma unroll
    for (int dt = 0; dt < 4; ++dt) {
#pragma unroll
        for (int rr = 0; rr < 4; ++rr) {
            int d0 = dt * 32 + rr * 8 + g * 4;
            int r0 = rr * 4;
            u32* dst = (u32*)(lO + ql * 136 + d0);
            dst[0] = pack_bf2(acc[dt][r0] * scale,     acc[dt][r0 + 1] * scale);
            dst[1] = pack_bf2(acc[dt][r0 + 2] * scale, acc[dt][r0 + 3] * scale);
        }
    }
    if (slot != 255 && g == 0) {
        const int sg = bh * 24 + slot;
        float2* pm = (float2*)pml + sg * 128 + (w * 32 + ql);
        *pm = make_float2(m_run, l_run);
    }
    __syncthreads();

    u16* gbase;
    size_t rstride;
    if (slot == 255) {
        gbase = obuf + (rowbase + qw) * 2048 + h * 128;
        rstride = 2048;
    } else {
        const int sg = bh * 24 + slot;
        gbase = pout + (size_t)sg * 16384 + (size_t)(w * 32) * 128;
        rstride = 128;
    }
    const int eo = (lane & 15) * 8;
#pragma unroll
    for (int pass = 0; pass < 8; ++pass) {
        const int row = pass * 4 + (lane >> 4);
        bf16x8 v = *(const bf16x8*)(lO + row * 136 + eo);
        *(bf16x8*)(gbase + (size_t)row * rstride + eo) = v;
    }
}

// ---------------- merge the KV-chunk partials (qt >= 6, fan-in 2 or 3) ------
__global__ __launch_bounds__(256) void attn_merge(
    const u16* __restrict__ pout, const float* __restrict__ pml,
    u16* __restrict__ obuf)
{
    const int bid = blockIdx.x;          // 320 = j(10) x bh(32)
    const int bh = bid & 31, j = bid >> 5;
    const int qt = 6 + j;
    const int b = bh >> 4, h = bh & 15;
    const int tid = threadIdx.x;
    const int f  = (qt < 12) ? 2 : 3;
    const int sb = (qt < 12) ? (qt - 6) * 2 : 12 + (qt - 12) * 3;
    const int base = bh * 24 + sb;
    const float C2 = 0.08838834764831845f * 1.44269504088896341f;
    const int eo = (tid & 15) * 8;

#pragma unroll
    for (int pass = 0; pass < 8; ++pass) {
        const int row = pass * 16 + (tid >> 4);   // qloc 0..127
        float mv[3], lv[3], wv[3];
        float ms = -1e30f;
#pragma unroll
        for (int i = 0; i < 3; ++i) {
            if (i < f) {
                float2 ml = ((const float2*)pml)[(base + i) * 128 + row];
                mv[i] = ml.x; lv[i] = ml.y;
                ms = fmaxf(ms, ml.x);
            }
        }
        float L = 0.f;
#pragma unroll
        for (int i = 0; i < 3; ++i) {
            if (i < f) {
                wv[i] = exp2f((mv[i] - ms) * C2);
                L += lv[i] * wv[i];
            }
        }
        const float inv = 1.0f / L;

        float o[8];
#pragma unroll
        for (int e = 0; e < 8; ++e) o[e] = 0.f;
#pragma unroll
        for (int i = 0; i < 3; ++i) {
            if (i < f) {
                bf16x8 v = *(const bf16x8*)(pout + (size_t)(base + i) * 16384
                                            + (size_t)row * 128 + eo);
#pragma unroll
                for (int e = 0; e < 8; ++e) o[e] += wv[i] * bf2f((u16)v[e]);
            }
        }
        u16* orow = obuf + ((size_t)b * 2048 + qt * 128 + row) * 2048 + h * 128 + eo;
#pragma unroll
        for (int e = 0; e < 8; e += 2)
            *(u32*)(orow + e) = pack_bf2(o[e] * inv, o[e + 1] * inv);
    }
}

extern "C" void kernel_launch(void* const* d_in, const int* in_sizes, int n_in,
                              void* d_out, int out_size, void* d_ws, size_t ws_size,
                              hipStream_t stream) {
    (void)in_sizes; (void)n_in; (void)out_size; (void)ws_size;
    const float* x    = (const float*)d_in[0];
    const float* Wqkv = (const float*)d_in[1];
    const float* bqkv = (const float*)d_in[2];
    const float* Wout = (const float*)d_in[3];
    const float* bout = (const float*)d_in[4];

    char* ws = (char*)d_ws;
    u16* xb  = (u16*)ws;                        // [4096,2048] bf16, 16 MB
    u16* wqb = (u16*)(ws + (size_t)16777216);   // [6144,2048] bf16, 24 MB
    u16* qkv = (u16*)(ws + (size_t)41943040);   // [4096,6144] bf16, 48 MB
    u16* ob  = xb;   // attention out reuses xb (x dead after GEMM1)
    u16* vtb = wqb;  // V^T [32,128,2048] bf16 16 MB reuses wqb
    u16* wob = wqb;  // W_out bf16 reuses wqb again (vtb dead after attn)
    float* pml = (float*)(ws + (size_t)33554432);  // 768KB in wqb tail hole
    u16* pO  = (u16*)d_out;  // 24 MB bf16 partials: d_out is free scratch
                             // until gemm2 overwrites it

    // fused x + Wqkv cast (one launch)
    cvt2_f32_bf16<<<2048, 256, 0, stream>>>(x, xb, 8388608L / 8,
                                            Wqkv, wqb, 12582912L / 8);
    // gemm1: T3-minimum 1-barrier loop, 128^2, 8 waves, grid 32x48=1536
    gemm128_1b<1><<<1536, 512, 0, stream>>>(xb, wqb, bqkv, qkv, 2048, 6144, 5);
    transpose_v<<<2048, 256, 0, stream>>>(qkv, vtb);
    attn_fwd<<<960, 256, 0, stream>>>(qkv, vtb, ob, pO, pml);
    attn_merge<<<320, 256, 0, stream>>>(pO, pml, ob);
    cvt_f32_bf16<<<2048, 256, 0, stream>>>(Wout, wob, 4194304L / 8);
    // gemm2: validated round-16 structure, f32 out, grid 32x16=512
    gemm128_8w<0><<<512, 512, 0, stream>>>(ob, wob, bout, d_out, 2048, 2048, 5);
}